// Round 7
// baseline (228.781 us; speedup 1.0000x reference)
//
#include <hip/hip_runtime.h>
#include <hip/hip_bf16.h>

#define BB 4
#define LL 2048
#define DM 1024
#define NH 16
#define FEAT 16
#define HD 64
#define CHUNK 128
#define NCHUNK 16
#define NEXT 65               // 64 v-cols + 1 ones-col (e=65..79 zeros dropped)
#define SROW 18720            // 18 dtiles x 65 e x 16 d = per-(bh,c) slab elems
#define EPS 1e-12f
#define INV_R2RD 0.17677669529663688f   // 1/(4*sqrt(2))
#define QKVLD 1536
#define LP 152                // state_kernel LDS row pad (us)

typedef short bf16x8_t __attribute__((ext_vector_type(8)));
typedef short bf16x4_t __attribute__((ext_vector_type(4)));
typedef float f32x4_t  __attribute__((ext_vector_type(4)));

__device__ __forceinline__ float b2f(unsigned short u) {
    union { unsigned int i; float f; } x; x.i = ((unsigned int)u) << 16; return x.f;
}
__device__ __forceinline__ unsigned short f2b(float f) {
    __hip_bfloat16 h = __float2bfloat16(f);
    return *reinterpret_cast<unsigned short*>(&h);
}

// ---------------------------------------------------------------------------
// One kernel for all fp32->bf16 casts (5 segments, compile-time boundaries).
// ---------------------------------------------------------------------------
__global__ __launch_bounds__(256)
void cast_all(const float* __restrict__ hs, const float* __restrict__ wq,
              const float* __restrict__ wk, const float* __restrict__ wv,
              const float* __restrict__ wo, unsigned short* __restrict__ hs_bf,
              unsigned short* __restrict__ wqkv, unsigned short* __restrict__ wo_bf)
{
    const int i = (blockIdx.x * 256 + threadIdx.x) * 4;
    const float* s; unsigned short* d;
    if (i < 8388608)       { s = hs + i;             d = hs_bf + i; }
    else if (i < 8650752)  { s = wq + (i - 8388608); d = wqkv + (i - 8388608); }
    else if (i < 8912896)  { s = wk + (i - 8650752); d = wqkv + 262144 + (i - 8650752); }
    else if (i < 9961472)  { s = wv + (i - 8912896); d = wqkv + 524288 + (i - 8912896); }
    else if (i < 11010048) { s = wo + (i - 9961472); d = wo_bf + (i - 9961472); }
    else return;
    float4 v = *(const float4*)s;
    ushort4 o; o.x = f2b(v.x); o.y = f2b(v.y); o.z = f2b(v.z); o.w = f2b(v.w);
    *(ushort4*)d = o;
}

// ---------------------------------------------------------------------------
// QKV GEMM: 256x192 tile, BK=64, 8-phase counted-vmcnt schedule. (unchanged)
// ---------------------------------------------------------------------------
__global__ __launch_bounds__(512, 2)
void gemm_bf16_192(const unsigned short* __restrict__ A, const unsigned short* __restrict__ Bw,
                   unsigned short* __restrict__ C, int K, int lda, int ldb, int ldc)
{
    __shared__ unsigned short lds[57344];   // 112 KiB
    const int tid  = threadIdx.x;
    const int wid  = tid >> 6, lane = tid & 63;
    const int wm   = wid >> 2, wn = wid & 3;
    const int ml   = lane & 15, quad = lane >> 4;
    const int nwg = gridDim.x * gridDim.y;
    const int lin = blockIdx.y * gridDim.x + blockIdx.x;
    const int swz_id = (lin & 7) * (nwg >> 3) + (lin >> 3);
    const int m0   = (swz_id / gridDim.x) * 256, n0 = (swz_id % gridDim.x) * 192;
    const int NT   = K >> 6;

    const int srow  = tid >> 3;
    const int scol  = ((tid & 7) ^ (srow & 7)) << 3;
    const int wbase = wid << 9;

    auto stage_unit = [&](int t, int isB, int u) {
        const unsigned short* g0 = isB ? Bw : A;
        const int ld = isB ? ldb : lda;
        const int rb = (isB ? n0 : m0) + u * 64 + srow;
        unsigned short* lb = lds + (isB ? 32768 + (t & 1) * 12288 : ((t & 1) << 14))
                             + (u << 12) + wbase;
        const unsigned short* g = g0 + (size_t)rb * ld + (t << 6) + scol;
        __builtin_amdgcn_global_load_lds((const __attribute__((address_space(1))) void*)g,
                                         (__attribute__((address_space(3))) void*)lb, 16, 0, 0);
    };

    f32x4_t acc[8][3];
#pragma unroll
    for (int i = 0; i < 8; ++i)
#pragma unroll
        for (int j = 0; j < 3; ++j) acc[i][j] = (f32x4_t){0.f, 0.f, 0.f, 0.f};

    stage_unit(0, 0, 0); stage_unit(0, 0, 1); stage_unit(0, 0, 2); stage_unit(0, 0, 3);
    stage_unit(0, 1, 0); stage_unit(0, 1, 1); stage_unit(0, 1, 2);
    stage_unit(1, 0, 0); stage_unit(1, 0, 1);
    stage_unit(1, 1, 0); stage_unit(1, 1, 1);
    stage_unit(1, 0, 2); stage_unit(1, 0, 3);
    asm volatile("s_waitcnt vmcnt(6)" ::: "memory");
    __builtin_amdgcn_s_barrier();

    const int swz  = (ml & 7) << 3;
    const int c0   = (quad << 3) ^ swz;
    const int c1   = (32 + (quad << 3)) ^ swz;
    const int arow = ml << 6;

    bf16x8_t aA[4][2], bLo[2][2], bN2[2];

    for (int t = 0; t < NT; ++t) {
        const int ab = (t & 1) << 14;
        const int bb = 32768 + (t & 1) * 12288;

        // ---- phase 0 ----
#pragma unroll
        for (int m = 0; m < 4; ++m) {
            const int r = ab + ((2 * m + wm) << 10) + arow;
            aA[m][0] = *(const bf16x8_t*)&lds[r + c0];
            aA[m][1] = *(const bf16x8_t*)&lds[r + c1];
        }
#pragma unroll
        for (int n = 0; n < 2; ++n) {
            const int r = bb + (wn * 48 + n * 16 + ml) * 64;
            bLo[n][0] = *(const bf16x8_t*)&lds[r + c0];
            bLo[n][1] = *(const bf16x8_t*)&lds[r + c1];
        }
        if (t + 1 < NT) stage_unit(t + 1, 1, 2);
        __builtin_amdgcn_s_barrier();
        asm volatile("s_waitcnt lgkmcnt(0)" ::: "memory");
        __builtin_amdgcn_sched_barrier(0);
        __builtin_amdgcn_s_setprio(1);
#pragma unroll
        for (int m = 0; m < 4; ++m)
#pragma unroll
            for (int n = 0; n < 2; ++n) {
                acc[m][n] = __builtin_amdgcn_mfma_f32_16x16x32_bf16(aA[m][0], bLo[n][0], acc[m][n], 0, 0, 0);
                acc[m][n] = __builtin_amdgcn_mfma_f32_16x16x32_bf16(aA[m][1], bLo[n][1], acc[m][n], 0, 0, 0);
            }
        __builtin_amdgcn_s_setprio(0);
        __builtin_amdgcn_s_barrier();

        // ---- phase 1 ----
        {
            const int r = bb + (wn * 48 + 32 + ml) * 64;
            bN2[0] = *(const bf16x8_t*)&lds[r + c0];
            bN2[1] = *(const bf16x8_t*)&lds[r + c1];
        }
        if (t + 2 < NT) { stage_unit(t + 2, 0, 0); stage_unit(t + 2, 0, 1); }
        __builtin_amdgcn_s_barrier();
        asm volatile("s_waitcnt lgkmcnt(0)" ::: "memory");
        __builtin_amdgcn_sched_barrier(0);
        __builtin_amdgcn_s_setprio(1);
#pragma unroll
        for (int m = 0; m < 4; ++m) {
            acc[m][2] = __builtin_amdgcn_mfma_f32_16x16x32_bf16(aA[m][0], bN2[0], acc[m][2], 0, 0, 0);
            acc[m][2] = __builtin_amdgcn_mfma_f32_16x16x32_bf16(aA[m][1], bN2[1], acc[m][2], 0, 0, 0);
        }
        __builtin_amdgcn_s_setprio(0);
        __builtin_amdgcn_s_barrier();

        // ---- phase 2 ----
#pragma unroll
        for (int m = 0; m < 4; ++m) {
            const int r = ab + ((2 * (m + 4) + wm) << 10) + arow;
            aA[m][0] = *(const bf16x8_t*)&lds[r + c0];
            aA[m][1] = *(const bf16x8_t*)&lds[r + c1];
        }
        if (t + 2 < NT) { stage_unit(t + 2, 1, 0); stage_unit(t + 2, 1, 1); }
        __builtin_amdgcn_s_barrier();
        asm volatile("s_waitcnt lgkmcnt(0)" ::: "memory");
        __builtin_amdgcn_sched_barrier(0);
        __builtin_amdgcn_s_setprio(1);
#pragma unroll
        for (int m = 0; m < 4; ++m)
#pragma unroll
            for (int n = 0; n < 2; ++n) {
                acc[4 + m][n] = __builtin_amdgcn_mfma_f32_16x16x32_bf16(aA[m][0], bLo[n][0], acc[4 + m][n], 0, 0, 0);
                acc[4 + m][n] = __builtin_amdgcn_mfma_f32_16x16x32_bf16(aA[m][1], bLo[n][1], acc[4 + m][n], 0, 0, 0);
            }
        __builtin_amdgcn_s_setprio(0);
        __builtin_amdgcn_s_barrier();

        // ---- phase 3 ----
        if (t + 2 < NT) { stage_unit(t + 2, 0, 2); stage_unit(t + 2, 0, 3); }
        __builtin_amdgcn_s_barrier();
        asm volatile("s_waitcnt lgkmcnt(0)" ::: "memory");
        __builtin_amdgcn_sched_barrier(0);
        __builtin_amdgcn_s_setprio(1);
#pragma unroll
        for (int m = 0; m < 4; ++m) {
            acc[4 + m][2] = __builtin_amdgcn_mfma_f32_16x16x32_bf16(aA[m][0], bN2[0], acc[4 + m][2], 0, 0, 0);
            acc[4 + m][2] = __builtin_amdgcn_mfma_f32_16x16x32_bf16(aA[m][1], bN2[1], acc[4 + m][2], 0, 0, 0);
        }
        __builtin_amdgcn_s_setprio(0);
        if (t + 2 < NT)      asm volatile("s_waitcnt vmcnt(6)" ::: "memory");
        else if (t + 1 < NT) asm volatile("s_waitcnt vmcnt(0)" ::: "memory");
        __builtin_amdgcn_s_barrier();
    }

#pragma unroll
    for (int m = 0; m < 8; ++m) {
        const int rbase = m0 + (2 * m + wm) * 16 + quad * 4;
#pragma unroll
        for (int n = 0; n < 3; ++n) {
            const int col = n0 + wn * 48 + n * 16 + ml;
#pragma unroll
            for (int r = 0; r < 4; ++r)
                C[(size_t)(rbase + r) * ldc + col] = f2b(acc[m][n][r]);
        }
    }
}

// ---------------------------------------------------------------------------
// 128x256-tile variant (fp32 out) for the output projection. (unchanged)
// ---------------------------------------------------------------------------
__global__ __launch_bounds__(512, 2)
void gemm_bf16_128x256(const unsigned short* __restrict__ A, const unsigned short* __restrict__ Bw,
                       float* __restrict__ C, int K, int lda, int ldb, int ldc)
{
    __shared__ unsigned short lds[49152];   // 96 KiB
    const int tid  = threadIdx.x;
    const int wid  = tid >> 6, lane = tid & 63;
    const int wm   = wid >> 2, wn = wid & 3;
    const int ml   = lane & 15, quad = lane >> 4;
    const int nwg = gridDim.x * gridDim.y;
    const int lin = blockIdx.y * gridDim.x + blockIdx.x;
    const int swz_id = (lin & 7) * (nwg >> 3) + (lin >> 3);
    const int m0   = (swz_id / gridDim.x) * 128, n0 = (swz_id % gridDim.x) * 256;
    const int NT   = K >> 6;

    const int srow  = tid >> 3;
    const int scol  = ((tid & 7) ^ (srow & 7)) << 3;
    const int wbase = wid << 9;

    auto stage_unit = [&](int t, int isB, int u) {
        const unsigned short* g0 = isB ? Bw : A;
        const int ld = isB ? ldb : lda;
        const int rb = (isB ? n0 : m0) + u * 64 + srow;
        const int k0 = t << 6;
        unsigned short* lb = lds + (isB ? 16384 : 0) + ((t & 1) << (isB ? 14 : 13))
                             + (u << 12) + wbase;
        const unsigned short* g = g0 + (size_t)rb * ld + k0 + scol;
        __builtin_amdgcn_global_load_lds((const __attribute__((address_space(1))) void*)g,
                                         (__attribute__((address_space(3))) void*)lb, 16, 0, 0);
    };

    f32x4_t acc[4][4];
#pragma unroll
    for (int i = 0; i < 4; ++i)
#pragma unroll
        for (int j = 0; j < 4; ++j) acc[i][j] = (f32x4_t){0.f, 0.f, 0.f, 0.f};

    stage_unit(0, 0, 0); stage_unit(0, 0, 1);
    stage_unit(0, 1, 0); stage_unit(0, 1, 1); stage_unit(0, 1, 2); stage_unit(0, 1, 3);
    stage_unit(1, 0, 0); stage_unit(1, 0, 1);
    stage_unit(1, 1, 0); stage_unit(1, 1, 1);
    asm volatile("s_waitcnt vmcnt(4)" ::: "memory");
    __builtin_amdgcn_s_barrier();

    const int swz  = (ml & 7) << 3;
    const int c0   = (quad << 3) ^ swz;
    const int c1   = (32 + (quad << 3)) ^ swz;
    const int arow = ml << 6;

    bf16x8_t aA[4][2], bF[2][2];

    for (int t = 0; t < NT; ++t) {
        const int ab = (t & 1) << 13;
        const int bb = 16384 + ((t & 1) << 14);

        // ---- phase 0 ----
#pragma unroll
        for (int m = 0; m < 4; ++m) {
            const int r = ab + ((2 * m + wm) << 10) + arow;
            aA[m][0] = *(const bf16x8_t*)&lds[r + c0];
            aA[m][1] = *(const bf16x8_t*)&lds[r + c1];
        }
#pragma unroll
        for (int n = 0; n < 2; ++n) {
            const int r = bb + ((4 * n + wn) << 10) + arow;
            bF[n][0] = *(const bf16x8_t*)&lds[r + c0];
            bF[n][1] = *(const bf16x8_t*)&lds[r + c1];
        }
        if (t + 1 < NT) { stage_unit(t + 1, 1, 2); stage_unit(t + 1, 1, 3); }
        __builtin_amdgcn_s_barrier();
        asm volatile("s_waitcnt lgkmcnt(0)" ::: "memory");
        __builtin_amdgcn_sched_barrier(0);
        __builtin_amdgcn_s_setprio(1);
#pragma unroll
        for (int m = 0; m < 4; ++m)
#pragma unroll
            for (int n = 0; n < 2; ++n) {
                acc[m][n] = __builtin_amdgcn_mfma_f32_16x16x32_bf16(aA[m][0], bF[n][0], acc[m][n], 0, 0, 0);
                acc[m][n] = __builtin_amdgcn_mfma_f32_16x16x32_bf16(aA[m][1], bF[n][1], acc[m][n], 0, 0, 0);
            }
        __builtin_amdgcn_s_setprio(0);
        __builtin_amdgcn_s_barrier();

        // ---- phase 1 ----
#pragma unroll
        for (int n = 0; n < 2; ++n) {
            const int r = bb + ((4 * (n + 2) + wn) << 10) + arow;
            bF[n][0] = *(const bf16x8_t*)&lds[r + c0];
            bF[n][1] = *(const bf16x8_t*)&lds[r + c1];
        }
        if (t + 2 < NT) {
            stage_unit(t + 2, 0, 0); stage_unit(t + 2, 0, 1);
            stage_unit(t + 2, 1, 0); stage_unit(t + 2, 1, 1);
        }
        __builtin_amdgcn_s_barrier();
        asm volatile("s_waitcnt lgkmcnt(0)" ::: "memory");
        __builtin_amdgcn_sched_barrier(0);
        __builtin_amdgcn_s_setprio(1);
#pragma unroll
        for (int m = 0; m < 4; ++m)
#pragma unroll
            for (int n = 0; n < 2; ++n) {
                acc[m][2 + n] = __builtin_amdgcn_mfma_f32_16x16x32_bf16(aA[m][0], bF[n][0], acc[m][2 + n], 0, 0, 0);
                acc[m][2 + n] = __builtin_amdgcn_mfma_f32_16x16x32_bf16(aA[m][1], bF[n][1], acc[m][2 + n], 0, 0, 0);
            }
        __builtin_amdgcn_s_setprio(0);
        if (t + 2 < NT)      asm volatile("s_waitcnt vmcnt(4)" ::: "memory");
        else if (t + 1 < NT) asm volatile("s_waitcnt vmcnt(0)" ::: "memory");
        __builtin_amdgcn_s_barrier();
    }

#pragma unroll
    for (int m = 0; m < 4; ++m) {
        const int rbase = m0 + (2 * m + wm) * 16 + quad * 4;
#pragma unroll
        for (int n = 0; n < 4; ++n) {
            const int col = n0 + (4 * n + wn) * 16 + ml;
#pragma unroll
            for (int r = 0; r < 4; ++r)
                C[(size_t)(rbase + r) * ldc + col] = acc[m][n][r];
        }
    }
}

// ---------------------------------------------------------------------------
// state_kernel: per (bh,c) computes S_c = Kf^T @ V_ext (MFMA). (unchanged)
// ---------------------------------------------------------------------------
__global__ __launch_bounds__(256)
void state_kernel(const unsigned short* __restrict__ qkv, unsigned short* __restrict__ STg)
{
    __shared__ unsigned short KT[16 * LP];   // K transposed [f][j]
    __shared__ unsigned short VT[80 * LP];   // V_ext transposed [e][j]

    const int x = blockIdx.x;
    const int c = x & 15, bh = x >> 4;
    const int b = bh >> 4, h = bh & 15;
    const int tid = threadIdx.x;
    const int wave = tid >> 6, lane = tid & 63;
    const int ml = lane & 15, kg8 = (lane >> 4) * 8;
    const int quad4 = (lane >> 4) * 4;
    const size_t rowbase = (size_t)(b * LL + c * CHUNK);
    const size_t Sbase = (size_t)x * SROW;

    {
        const int rg = tid & 31, eb = tid >> 5;   // rows 4rg..4rg+3, e-block eb*8
        uint4 vv[4];
#pragma unroll
        for (int i = 0; i < 4; ++i)
            vv[i] = *(const uint4*)(qkv + (rowbase + 4 * rg + i) * QKVLD + 512 + h * 64 + eb * 8);
        const unsigned short* p0 = (const unsigned short*)&vv[0];
        const unsigned short* p1 = (const unsigned short*)&vv[1];
        const unsigned short* p2 = (const unsigned short*)&vv[2];
        const unsigned short* p3 = (const unsigned short*)&vv[3];
#pragma unroll
        for (int e = 0; e < 8; ++e) {
            ushort4 w4; w4.x = p0[e]; w4.y = p1[e]; w4.z = p2[e]; w4.w = p3[e];
            *(ushort4*)&VT[(eb * 8 + e) * LP + 4 * rg] = w4;
        }
        if (eb < 2) {   // K: 16 feature rows via tid<64
            uint4 kv4[4];
#pragma unroll
            for (int i = 0; i < 4; ++i)
                kv4[i] = *(const uint4*)(qkv + (rowbase + 4 * rg + i) * QKVLD + 256 + h * 16 + eb * 8);
            const unsigned short* k0 = (const unsigned short*)&kv4[0];
            const unsigned short* k1 = (const unsigned short*)&kv4[1];
            const unsigned short* k2 = (const unsigned short*)&kv4[2];
            const unsigned short* k3 = (const unsigned short*)&kv4[3];
#pragma unroll
            for (int e = 0; e < 8; ++e) {
                ushort4 w4; w4.x = k0[e]; w4.y = k1[e]; w4.z = k2[e]; w4.w = k3[e];
                *(ushort4*)&KT[(eb * 8 + e) * LP + 4 * rg] = w4;
            }
        }
        const int row = tid >> 1, half = tid & 1;
        if (half == 0) {
            VT[64 * LP + row] = 0x3F80;   // ones column
        } else {
#pragma unroll
            for (int e = 65; e < 80; ++e) VT[e * LP + row] = 0;
        }
    }
    __syncthreads();

    bf16x8_t bfr[5][4];
#pragma unroll
    for (int nt = 0; nt < 5; ++nt)
#pragma unroll
        for (int ks = 0; ks < 4; ++ks)
            bfr[nt][ks] = *(const bf16x8_t*)&VT[(nt * 16 + ml) * LP + ks * 32 + kg8];

    for (int mt = wave; mt < 18; mt += 4) {
        const int d = mt * 16 + ml;
        bf16x8_t af[4];
#pragma unroll
        for (int ks = 0; ks < 4; ++ks) {
            const int jb = ks * 32 + kg8;
            unsigned short o[8];
            if (d >= 24 && d < 280) {
                const int e = d - 24, a = e >> 4, bq = e & 15;
                bf16x8_t ka = *(const bf16x8_t*)&KT[a  * LP + jb];
                bf16x8_t kb = *(const bf16x8_t*)&KT[bq * LP + jb];
#pragma unroll
                for (int j = 0; j < 8; ++j)
                    o[j] = f2b(b2f((unsigned short)ka[j]) * b2f((unsigned short)kb[j]) * INV_R2RD);
            } else if (d == 0) {
#pragma unroll
                for (int j = 0; j < 8; ++j) o[j] = 0x3F80;
            } else if (d <= 16) {
                bf16x8_t kx = *(const bf16x8_t*)&KT[(d - 1) * LP + jb];
#pragma unroll
                for (int j = 0; j < 8; ++j) o[j] = f2b(b2f((unsigned short)kx[j]) * 0.5f);
            } else {
#pragma unroll
                for (int j = 0; j < 8; ++j) o[j] = 0;
            }
            af[ks] = *(const bf16x8_t*)o;
        }
        f32x4_t acc[5];
#pragma unroll
        for (int nt = 0; nt < 5; ++nt) acc[nt] = (f32x4_t){0.f, 0.f, 0.f, 0.f};
        __builtin_amdgcn_s_setprio(1);
#pragma unroll
        for (int nt = 0; nt < 5; ++nt)
#pragma unroll
            for (int ks = 0; ks < 4; ++ks)
                acc[nt] = __builtin_amdgcn_mfma_f32_16x16x32_bf16(af[ks], bfr[nt][ks], acc[nt], 0, 0, 0);
        __builtin_amdgcn_s_setprio(0);
#pragma unroll
        for (int nt = 0; nt < 5; ++nt) {
            ushort4 pk;
            pk.x = f2b(acc[nt][0]); pk.y = f2b(acc[nt][1]);
            pk.z = f2b(acc[nt][2]); pk.w = f2b(acc[nt][3]);
            if (nt < 4) {
                *(ushort4*)(STg + Sbase + (size_t)mt * 1040 + (nt * 16 + ml) * 16 + quad4) = pk;
            } else if (ml == 0) {
                *(ushort4*)(STg + Sbase + (size_t)mt * 1040 + 1024 + quad4) = pk;
            }
        }
    }
}

// ---------------------------------------------------------------------------
// scan: exclusive prefix over the 16 chunks, elementwise. (unchanged)
// ---------------------------------------------------------------------------
__global__ __launch_bounds__(256)
void scan_S(unsigned short* __restrict__ STg) {
    const int bh  = blockIdx.y;
    const int idx = blockIdx.x * 256 + threadIdx.x;   // uint4 index, 0..2339
    if (idx >= SROW / 8) return;
    const size_t base = (size_t)bh * NCHUNK * SROW + (size_t)idx * 8;
    uint4 v[NCHUNK];
#pragma unroll
    for (int c = 0; c < NCHUNK; ++c)
        v[c] = *(const uint4*)(STg + base + (size_t)c * SROW);
    float acc[8] = {};
#pragma unroll
    for (int c = 0; c < NCHUNK; ++c) {
        const unsigned short* vp = (const unsigned short*)&v[c];
        uint4 o;
        unsigned short* op = (unsigned short*)&o;
#pragma unroll
        for (int i = 0; i < 8; ++i) { op[i] = f2b(acc[i]); acc[i] += b2f(vp[i]); }
        *(uint4*)(STg + base + (size_t)c * SROW) = o;
    }
}

// ---------------------------------------------------------------------------
// out_kernel: per (bh,c), 256 threads / 4 waves.  LDS 53536 B -> 3 blocks/CU.
// r7: phase-2b ST ring deepened to 4 slots / 3-deep prefetch (VGPR headroom
// from r6's occupancy work: ~124 used vs ~168 cap at 3 blocks/CU).  Slices
// 0..2 issued at kernel top (in flight through phase 1), slice 3 before 2a;
// in-loop ldst(kq+4) recycles slot kq&3 right after its consuming MFMAs.
// ---------------------------------------------------------------------------
#define OFF_QP 0
#define OFF_KP 3088
#define OFF_VT 0
#define LPVT   144
#define OFF_A  9360
#define LPA    136

__global__ __launch_bounds__(256, 3)
void out_kernel(const unsigned short* __restrict__ qkv_ro, const unsigned short* __restrict__ STg,
                unsigned short* __restrict__ qkv_w)
{
    __shared__ unsigned short smem[26768];   // 53536 B -> 3 blocks/CU

    const int x = blockIdx.x;
    const int c = x & 15, bh = x >> 4;
    const int b = bh >> 4, h = bh & 15;
    const int tid = threadIdx.x;
    const int w = tid >> 6, lane = tid & 63;
    const int ml = lane & 15, quad = lane >> 4, kg8 = quad * 8;
    const size_t rowbase = (size_t)(b * LL + c * CHUNK);
    const size_t Sbase = (size_t)x * SROW;

    // ---- ST slice loader: tiled slab, per-mt stride 1040, per-kq 2080 ----
    const unsigned short* stp = STg + Sbase + (size_t)(quad >> 1) * 1040 + (quad & 1) * 8;
    bf16x8_t stf[4][5];
    auto ldst = [&](int kq, int slot) {
#pragma unroll
        for (int nt = 0; nt < 5; ++nt)
            stf[slot][nt] = *(const bf16x8_t*)(stp + (size_t)kq * 2080 + (nt * 16 + ml) * 16);
    };

    // ---- issue ALL long-latency loads up front (T14), coalesced ----
    const int row = tid >> 1, half = tid & 1;
    uint4 qv = *(const uint4*)(qkv_ro + (rowbase + row) * QKVLD + h * 16 + half * 8);
    uint4 kv = *(const uint4*)(qkv_ro + (rowbase + row) * QKVLD + 256 + h * 16 + half * 8);
    uint4 vreg[4];
#pragma unroll
    for (int cc = 0; cc < 4; ++cc)
        vreg[cc] = *(const uint4*)(qkv_ro + (rowbase + row) * QKVLD + 512 + h * 64 + half * 32 + cc * 8);
    ldst(0, 0);
    ldst(1, 1);
    ldst(2, 2);

    // ---- stage Q (packed, stride 24) and K (padded, stride 40) ----
    *(uint4*)&smem[OFF_QP + row * 24 + half * 8] = qv;                       // cols 0..15
    if (half == 0) *(uint4*)&smem[OFF_QP + row * 24 + 16] = (uint4){0,0,0,0}; // cols 16..23
    if (tid < 16) smem[OFF_QP + 3072 + tid] = 0;                              // tail pad
    *(uint4*)&smem[OFF_KP + row * 40 + half * 8] = kv;
    *(uint4*)&smem[OFF_KP + row * 40 + 16 + half * 8] = (uint4){0, 0, 0, 0};  // K zero cols
    __syncthreads();

    // ---- phase 1: scores ----
    {
        bf16x8_t q0 = *(const bf16x8_t*)&smem[OFF_QP + (w * 32 + ml) * 24 + kg8];
        bf16x8_t q1 = *(const bf16x8_t*)&smem[OFF_QP + (w * 32 + 16 + ml) * 24 + kg8];
#pragma unroll
        for (int nt = 0; nt < 8; ++nt) {
            bf16x8_t kf = *(const bf16x8_t*)&smem[OFF_KP + (nt * 16 + ml) * 40 + kg8];
            f32x4_t a0 = __builtin_amdgcn_mfma_f32_16x16x32_bf16(q0, kf, (f32x4_t){0,0,0,0}, 0, 0, 0);
            f32x4_t a1 = __builtin_amdgcn_mfma_f32_16x16x32_bf16(q1, kf, (f32x4_t){0,0,0,0}, 0, 0, 0);
            const int j = nt * 16 + ml;
#pragma unroll
            for (int r = 0; r < 4; ++r) {
                int i0 = w * 32 + quad * 4 + r;
                float s0 = a0[r] * 0.25f;
                float v0 = (j <= i0) ? (1.f + s0 + 0.5f * s0 * s0) : 0.f;
                smem[OFF_A + i0 * LPA + j] = f2b(v0);
                int i1 = i0 + 16;
                float s1 = a1[r] * 0.25f;
                float v1 = (j <= i1) ? (1.f + s1 + 0.5f * s1 * s1) : 0.f;
                smem[OFF_A + i1 * LPA + j] = f2b(v1);
            }
        }
    }
    // q f32 registers for Qf build (from QP, still alive before VT overlay)
    const int r0 = w * 32 + ml, r1 = r0 + 16;
    float qA[16], qB[16];
    {
#pragma unroll
        for (int i = 0; i < 4; ++i) {
            bf16x4_t u = *(const bf16x4_t*)&smem[OFF_QP + r0 * 24 + 4 * i];
            bf16x4_t v = *(const bf16x4_t*)&smem[OFF_QP + r1 * 24 + 4 * i];
#pragma unroll
            for (int j = 0; j < 4; ++j) {
                qA[4 * i + j] = b2f((unsigned short)u[j]);
                qB[4 * i + j] = b2f((unsigned short)v[j]);
            }
        }
    }
    // quad-parity q-half select, loop-invariant over kq (hoisted)
    float qselA[8], qselB[8];
#pragma unroll
    for (int j = 0; j < 8; ++j) {
        qselA[j] = (quad & 1) ? qA[j] : qA[8 + j];
        qselB[j] = (quad & 1) ? qB[j] : qB[8 + j];
    }
    __syncthreads();   // A-writes + QP/KP reads done before VT overlay

    // ---- write VT rows 0..64 (overlays QP/KP) from registers ----
    {
#pragma unroll
        for (int cc = 0; cc < 4; ++cc) {
            const unsigned short* vp = (const unsigned short*)&vreg[cc];
#pragma unroll
            for (int i = 0; i < 8; ++i) smem[OFF_VT + (half * 32 + cc * 8 + i) * LPVT + row] = vp[i];
        }
        if (half == 0) smem[OFF_VT + 64 * LPVT + row] = 0x3F80;   // ones row
    }
    __syncthreads();

    f32x4_t acc[2][5];
#pragma unroll
    for (int mt = 0; mt < 2; ++mt)
#pragma unroll
        for (int nt = 0; nt < 5; ++nt) acc[mt][nt] = (f32x4_t){0.f, 0.f, 0.f, 0.f};

    // prefetch ST slice kq=3 (slot 3) before phase 2a
    ldst(3, 3);

    const bf16x8_t vzero = (bf16x8_t){0, 0, 0, 0, 0, 0, 0, 0};

    // ---- phase 2a: A @ V_ext ----
#pragma unroll
    for (int ks = 0; ks < 4; ++ks) {
        bf16x8_t af0 = *(const bf16x8_t*)&smem[OFF_A + (w * 32 + ml) * LPA + ks * 32 + kg8];
        bf16x8_t af1 = *(const bf16x8_t*)&smem[OFF_A + (w * 32 + 16 + ml) * LPA + ks * 32 + kg8];
        __builtin_amdgcn_s_setprio(1);
#pragma unroll
        for (int nt = 0; nt < 4; ++nt) {
            bf16x8_t bv = *(const bf16x8_t*)&smem[OFF_VT + (nt * 16 + ml) * LPVT + ks * 32 + kg8];
            acc[0][nt] = __builtin_amdgcn_mfma_f32_16x16x32_bf16(af0, bv, acc[0][nt], 0, 0, 0);
            acc[1][nt] = __builtin_amdgcn_mfma_f32_16x16x32_bf16(af1, bv, acc[1][nt], 0, 0, 0);
        }
        bf16x8_t bv4 = vzero;   // rows 65..79 are structural zeros; only ml==0 has data
        if (ml == 0) bv4 = *(const bf16x8_t*)&smem[OFF_VT + 64 * LPVT + ks * 32 + kg8];
        acc[0][4] = __builtin_amdgcn_mfma_f32_16x16x32_bf16(af0, bv4, acc[0][4], 0, 0, 0);
        acc[1][4] = __builtin_amdgcn_mfma_f32_16x16x32_bf16(af1, bv4, acc[1][4], 0, 0, 0);
        __builtin_amdgcn_s_setprio(0);
    }

    // ---- phase 2b: Qf @ S_ext, 4-slot ring, 3-deep prefetch ----
#pragma unroll
    for (int kq = 0; kq < 9; ++kq) {
        bf16x8_t qf[2];
#pragma unroll
        for (int mt = 0; mt < 2; ++mt) {
            const float* q    = (mt == 0) ? qA : qB;
            const float* qsel = (mt == 0) ? qselA : qselB;
            const int d0 = kq * 32 + kg8;
            unsigned short o[8];
            if (d0 >= 24 && d0 < 280) {
                const int i2 = 2 * kq;
                const float base = (quad == 3) ? q[i2 > 15 ? 15 : i2]
                                 : (quad == 0) ? q[i2 < 2 ? 0 : i2 - 2]
                                               : q[i2 < 1 ? 0 : i2 - 1];
                const float qa = base * INV_R2RD;
#pragma unroll
                for (int j = 0; j < 8; ++j) o[j] = f2b(qa * qsel[j]);
            } else if (d0 == 0) {
                o[0] = 0x3F80;
#pragma unroll
                for (int j = 1; j < 8; ++j) o[j] = f2b(q[j - 1] * 0.5f);
            } else if (d0 == 8) {
#pragma unroll
                for (int j = 0; j < 8; ++j) o[j] = f2b(q[7 + j] * 0.5f);
            } else if (d0 == 16) {
                o[0] = f2b(q[15] * 0.5f);
#pragma unroll
                for (int j = 1; j < 8; ++j) o[j] = 0;
            } else {
#pragma unroll
                for (int j = 0; j < 8; ++j) o[j] = 0;
            }
            qf[mt] = *(const bf16x8_t*)o;
        }
        __builtin_amdgcn_s_setprio(1);
#pragma unroll
        for (int nt = 0; nt < 5; ++nt) {
            acc[0][nt] = __builtin_amdgcn_mfma_f32_16x16x32_bf16(qf[0], stf[kq & 3][nt], acc[0][nt], 0, 0, 0);
            acc[1][nt] = __builtin_amdgcn_mfma_f32_16x16x32_bf16(qf[1], stf[kq & 3][nt], acc[1][nt], 0, 0, 0);
        }
        __builtin_amdgcn_s_setprio(0);
        if (kq + 4 < 9) ldst(kq + 4, kq & 3);   // recycle just-consumed slot
    }

    // ---- epilogue: y = num / (den + eps), den = col 64 (nt=4, ml==0 lanes) ----
#pragma unroll
    for (int mt = 0; mt < 2; ++mt) {
        float den[4];
#pragma unroll
        for (int r = 0; r < 4; ++r) den[r] = __shfl(acc[mt][4][r], lane & 48);
#pragma unroll
        for (int r = 0; r < 4; ++r) {
            const size_t grow = rowbase + w * 32 + mt * 16 + quad * 4 + r;
            const float rc = 1.f / (den[r] + EPS);
#pragma unroll
            for (int nt = 0; nt < 4; ++nt)
                qkv_w[grow * QKVLD + 512 + h * 64 + nt * 16 + ml] = f2b(acc[mt][nt][r] * rc);
        }
    }
}

// ---------------------------------------------------------------------------
extern "C" void kernel_launch(void* const* d_in, const int* in_sizes, int n_in,
                              void* d_out, int out_size, void* d_ws, size_t ws_size,
                              hipStream_t stream)
{
    (void)in_sizes; (void)n_in; (void)out_size; (void)ws_size;
    const float* hs = (const float*)d_in[0];
    const float* Wq = (const float*)d_in[1];
    const float* Wk = (const float*)d_in[2];
    const float* Wv = (const float*)d_in[3];
    const float* Wo = (const float*)d_in[4];
    float* out = (float*)d_out;

    char* ws = (char*)d_ws;
    unsigned short* STg   = (unsigned short*)ws;
    unsigned short* hs_bf = (unsigned short*)ws;
    size_t off = 47185920;
    unsigned short* qkv   = (unsigned short*)(ws + off); off += 25165824;  // 8192x1536
    unsigned short* Wqkv  = (unsigned short*)(ws + off); off += 3145728;   // 1536x1024
    unsigned short* Wo_bf = (unsigned short*)(ws + off); off += 2097152;   // total 77.6 MB

    cast_all<<<10752, 256, 0, stream>>>(hs, Wq, Wk, Wv, Wo, hs_bf, Wqkv, Wo_bf);
    gemm_bf16_192<<<dim3(8, 32), 512, 0, stream>>>(hs_bf, Wqkv, qkv,
                                                   DM, DM, DM, QKVLD);
    state_kernel<<<1024, 256, 0, stream>>>(qkv, STg);
    scan_S<<<dim3(10, 64), 256, 0, stream>>>(STg);
    out_kernel<<<1024, 256, 0, stream>>>(qkv, STg, qkv);   // y in-place over v cols
    gemm_bf16_128x256<<<dim3(4, 64), 512, 0, stream>>>(qkv + 512, Wo_bf, out,
                                                       DM, QKVLD, DM, DM);
}

// Round 8
// 208.908 us; speedup vs baseline: 1.0951x; 1.0951x over previous
//
#include <hip/hip_runtime.h>
#include <hip/hip_bf16.h>

#define BB 4
#define LL 2048
#define DM 1024
#define NH 16
#define FEAT 16
#define HD 64
#define CHUNK 128
#define NCHUNK 16
#define NEXT 65               // 64 v-cols + 1 ones-col (e=65..79 zeros dropped)
#define SROW 18720            // 18 dtiles x 65 e x 16 d = per-(bh,c) slab elems
#define EPS 1e-12f
#define INV_R2RD 0.17677669529663688f   // 1/(4*sqrt(2))
#define QKVLD 1536
#define LP 152                // state_kernel LDS row pad (us)

typedef short bf16x8_t __attribute__((ext_vector_type(8)));
typedef short bf16x4_t __attribute__((ext_vector_type(4)));
typedef float f32x4_t  __attribute__((ext_vector_type(4)));

__device__ __forceinline__ float b2f(unsigned short u) {
    union { unsigned int i; float f; } x; x.i = ((unsigned int)u) << 16; return x.f;
}
__device__ __forceinline__ unsigned short f2b(float f) {
    __hip_bfloat16 h = __float2bfloat16(f);
    return *reinterpret_cast<unsigned short*>(&h);
}

// ---------------------------------------------------------------------------
// One kernel for all fp32->bf16 casts (5 segments, compile-time boundaries).
// ---------------------------------------------------------------------------
__global__ __launch_bounds__(256)
void cast_all(const float* __restrict__ hs, const float* __restrict__ wq,
              const float* __restrict__ wk, const float* __restrict__ wv,
              const float* __restrict__ wo, unsigned short* __restrict__ hs_bf,
              unsigned short* __restrict__ wqkv, unsigned short* __restrict__ wo_bf)
{
    const int i = (blockIdx.x * 256 + threadIdx.x) * 4;
    const float* s; unsigned short* d;
    if (i < 8388608)       { s = hs + i;             d = hs_bf + i; }
    else if (i < 8650752)  { s = wq + (i - 8388608); d = wqkv + (i - 8388608); }
    else if (i < 8912896)  { s = wk + (i - 8650752); d = wqkv + 262144 + (i - 8650752); }
    else if (i < 9961472)  { s = wv + (i - 8912896); d = wqkv + 524288 + (i - 8912896); }
    else if (i < 11010048) { s = wo + (i - 9961472); d = wo_bf + (i - 9961472); }
    else return;
    float4 v = *(const float4*)s;
    ushort4 o; o.x = f2b(v.x); o.y = f2b(v.y); o.z = f2b(v.z); o.w = f2b(v.w);
    *(ushort4*)d = o;
}

// ---------------------------------------------------------------------------
// QKV GEMM: 256x192 tile, BK=64, 8-phase counted-vmcnt schedule. (unchanged)
// ---------------------------------------------------------------------------
__global__ __launch_bounds__(512, 2)
void gemm_bf16_192(const unsigned short* __restrict__ A, const unsigned short* __restrict__ Bw,
                   unsigned short* __restrict__ C, int K, int lda, int ldb, int ldc)
{
    __shared__ unsigned short lds[57344];   // 112 KiB
    const int tid  = threadIdx.x;
    const int wid  = tid >> 6, lane = tid & 63;
    const int wm   = wid >> 2, wn = wid & 3;
    const int ml   = lane & 15, quad = lane >> 4;
    const int nwg = gridDim.x * gridDim.y;
    const int lin = blockIdx.y * gridDim.x + blockIdx.x;
    const int swz_id = (lin & 7) * (nwg >> 3) + (lin >> 3);
    const int m0   = (swz_id / gridDim.x) * 256, n0 = (swz_id % gridDim.x) * 192;
    const int NT   = K >> 6;

    const int srow  = tid >> 3;
    const int scol  = ((tid & 7) ^ (srow & 7)) << 3;
    const int wbase = wid << 9;

    auto stage_unit = [&](int t, int isB, int u) {
        const unsigned short* g0 = isB ? Bw : A;
        const int ld = isB ? ldb : lda;
        const int rb = (isB ? n0 : m0) + u * 64 + srow;
        unsigned short* lb = lds + (isB ? 32768 + (t & 1) * 12288 : ((t & 1) << 14))
                             + (u << 12) + wbase;
        const unsigned short* g = g0 + (size_t)rb * ld + (t << 6) + scol;
        __builtin_amdgcn_global_load_lds((const __attribute__((address_space(1))) void*)g,
                                         (__attribute__((address_space(3))) void*)lb, 16, 0, 0);
    };

    f32x4_t acc[8][3];
#pragma unroll
    for (int i = 0; i < 8; ++i)
#pragma unroll
        for (int j = 0; j < 3; ++j) acc[i][j] = (f32x4_t){0.f, 0.f, 0.f, 0.f};

    stage_unit(0, 0, 0); stage_unit(0, 0, 1); stage_unit(0, 0, 2); stage_unit(0, 0, 3);
    stage_unit(0, 1, 0); stage_unit(0, 1, 1); stage_unit(0, 1, 2);
    stage_unit(1, 0, 0); stage_unit(1, 0, 1);
    stage_unit(1, 1, 0); stage_unit(1, 1, 1);
    stage_unit(1, 0, 2); stage_unit(1, 0, 3);
    asm volatile("s_waitcnt vmcnt(6)" ::: "memory");
    __builtin_amdgcn_s_barrier();

    const int swz  = (ml & 7) << 3;
    const int c0   = (quad << 3) ^ swz;
    const int c1   = (32 + (quad << 3)) ^ swz;
    const int arow = ml << 6;

    bf16x8_t aA[4][2], bLo[2][2], bN2[2];

    for (int t = 0; t < NT; ++t) {
        const int ab = (t & 1) << 14;
        const int bb = 32768 + (t & 1) * 12288;

        // ---- phase 0 ----
#pragma unroll
        for (int m = 0; m < 4; ++m) {
            const int r = ab + ((2 * m + wm) << 10) + arow;
            aA[m][0] = *(const bf16x8_t*)&lds[r + c0];
            aA[m][1] = *(const bf16x8_t*)&lds[r + c1];
        }
#pragma unroll
        for (int n = 0; n < 2; ++n) {
            const int r = bb + (wn * 48 + n * 16 + ml) * 64;
            bLo[n][0] = *(const bf16x8_t*)&lds[r + c0];
            bLo[n][1] = *(const bf16x8_t*)&lds[r + c1];
        }
        if (t + 1 < NT) stage_unit(t + 1, 1, 2);
        __builtin_amdgcn_s_barrier();
        asm volatile("s_waitcnt lgkmcnt(0)" ::: "memory");
        __builtin_amdgcn_sched_barrier(0);
        __builtin_amdgcn_s_setprio(1);
#pragma unroll
        for (int m = 0; m < 4; ++m)
#pragma unroll
            for (int n = 0; n < 2; ++n) {
                acc[m][n] = __builtin_amdgcn_mfma_f32_16x16x32_bf16(aA[m][0], bLo[n][0], acc[m][n], 0, 0, 0);
                acc[m][n] = __builtin_amdgcn_mfma_f32_16x16x32_bf16(aA[m][1], bLo[n][1], acc[m][n], 0, 0, 0);
            }
        __builtin_amdgcn_s_setprio(0);
        __builtin_amdgcn_s_barrier();

        // ---- phase 1 ----
        {
            const int r = bb + (wn * 48 + 32 + ml) * 64;
            bN2[0] = *(const bf16x8_t*)&lds[r + c0];
            bN2[1] = *(const bf16x8_t*)&lds[r + c1];
        }
        if (t + 2 < NT) { stage_unit(t + 2, 0, 0); stage_unit(t + 2, 0, 1); }
        __builtin_amdgcn_s_barrier();
        asm volatile("s_waitcnt lgkmcnt(0)" ::: "memory");
        __builtin_amdgcn_sched_barrier(0);
        __builtin_amdgcn_s_setprio(1);
#pragma unroll
        for (int m = 0; m < 4; ++m) {
            acc[m][2] = __builtin_amdgcn_mfma_f32_16x16x32_bf16(aA[m][0], bN2[0], acc[m][2], 0, 0, 0);
            acc[m][2] = __builtin_amdgcn_mfma_f32_16x16x32_bf16(aA[m][1], bN2[1], acc[m][2], 0, 0, 0);
        }
        __builtin_amdgcn_s_setprio(0);
        __builtin_amdgcn_s_barrier();

        // ---- phase 2 ----
#pragma unroll
        for (int m = 0; m < 4; ++m) {
            const int r = ab + ((2 * (m + 4) + wm) << 10) + arow;
            aA[m][0] = *(const bf16x8_t*)&lds[r + c0];
            aA[m][1] = *(const bf16x8_t*)&lds[r + c1];
        }
        if (t + 2 < NT) { stage_unit(t + 2, 1, 0); stage_unit(t + 2, 1, 1); }
        __builtin_amdgcn_s_barrier();
        asm volatile("s_waitcnt lgkmcnt(0)" ::: "memory");
        __builtin_amdgcn_sched_barrier(0);
        __builtin_amdgcn_s_setprio(1);
#pragma unroll
        for (int m = 0; m < 4; ++m)
#pragma unroll
            for (int n = 0; n < 2; ++n) {
                acc[4 + m][n] = __builtin_amdgcn_mfma_f32_16x16x32_bf16(aA[m][0], bLo[n][0], acc[4 + m][n], 0, 0, 0);
                acc[4 + m][n] = __builtin_amdgcn_mfma_f32_16x16x32_bf16(aA[m][1], bLo[n][1], acc[4 + m][n], 0, 0, 0);
            }
        __builtin_amdgcn_s_setprio(0);
        __builtin_amdgcn_s_barrier();

        // ---- phase 3 ----
        if (t + 2 < NT) { stage_unit(t + 2, 0, 2); stage_unit(t + 2, 0, 3); }
        __builtin_amdgcn_s_barrier();
        asm volatile("s_waitcnt lgkmcnt(0)" ::: "memory");
        __builtin_amdgcn_sched_barrier(0);
        __builtin_amdgcn_s_setprio(1);
#pragma unroll
        for (int m = 0; m < 4; ++m) {
            acc[4 + m][2] = __builtin_amdgcn_mfma_f32_16x16x32_bf16(aA[m][0], bN2[0], acc[4 + m][2], 0, 0, 0);
            acc[4 + m][2] = __builtin_amdgcn_mfma_f32_16x16x32_bf16(aA[m][1], bN2[1], acc[4 + m][2], 0, 0, 0);
        }
        __builtin_amdgcn_s_setprio(0);
        if (t + 2 < NT)      asm volatile("s_waitcnt vmcnt(6)" ::: "memory");
        else if (t + 1 < NT) asm volatile("s_waitcnt vmcnt(0)" ::: "memory");
        __builtin_amdgcn_s_barrier();
    }

#pragma unroll
    for (int m = 0; m < 8; ++m) {
        const int rbase = m0 + (2 * m + wm) * 16 + quad * 4;
#pragma unroll
        for (int n = 0; n < 3; ++n) {
            const int col = n0 + wn * 48 + n * 16 + ml;
#pragma unroll
            for (int r = 0; r < 4; ++r)
                C[(size_t)(rbase + r) * ldc + col] = f2b(acc[m][n][r]);
        }
    }
}

// ---------------------------------------------------------------------------
// 128x256-tile variant (fp32 out) for the output projection. (unchanged)
// ---------------------------------------------------------------------------
__global__ __launch_bounds__(512, 2)
void gemm_bf16_128x256(const unsigned short* __restrict__ A, const unsigned short* __restrict__ Bw,
                       float* __restrict__ C, int K, int lda, int ldb, int ldc)
{
    __shared__ unsigned short lds[49152];   // 96 KiB
    const int tid  = threadIdx.x;
    const int wid  = tid >> 6, lane = tid & 63;
    const int wm   = wid >> 2, wn = wid & 3;
    const int ml   = lane & 15, quad = lane >> 4;
    const int nwg = gridDim.x * gridDim.y;
    const int lin = blockIdx.y * gridDim.x + blockIdx.x;
    const int swz_id = (lin & 7) * (nwg >> 3) + (lin >> 3);
    const int m0   = (swz_id / gridDim.x) * 128, n0 = (swz_id % gridDim.x) * 256;
    const int NT   = K >> 6;

    const int srow  = tid >> 3;
    const int scol  = ((tid & 7) ^ (srow & 7)) << 3;
    const int wbase = wid << 9;

    auto stage_unit = [&](int t, int isB, int u) {
        const unsigned short* g0 = isB ? Bw : A;
        const int ld = isB ? ldb : lda;
        const int rb = (isB ? n0 : m0) + u * 64 + srow;
        const int k0 = t << 6;
        unsigned short* lb = lds + (isB ? 16384 : 0) + ((t & 1) << (isB ? 14 : 13))
                             + (u << 12) + wbase;
        const unsigned short* g = g0 + (size_t)rb * ld + k0 + scol;
        __builtin_amdgcn_global_load_lds((const __attribute__((address_space(1))) void*)g,
                                         (__attribute__((address_space(3))) void*)lb, 16, 0, 0);
    };

    f32x4_t acc[4][4];
#pragma unroll
    for (int i = 0; i < 4; ++i)
#pragma unroll
        for (int j = 0; j < 4; ++j) acc[i][j] = (f32x4_t){0.f, 0.f, 0.f, 0.f};

    stage_unit(0, 0, 0); stage_unit(0, 0, 1);
    stage_unit(0, 1, 0); stage_unit(0, 1, 1); stage_unit(0, 1, 2); stage_unit(0, 1, 3);
    stage_unit(1, 0, 0); stage_unit(1, 0, 1);
    stage_unit(1, 1, 0); stage_unit(1, 1, 1);
    asm volatile("s_waitcnt vmcnt(4)" ::: "memory");
    __builtin_amdgcn_s_barrier();

    const int swz  = (ml & 7) << 3;
    const int c0   = (quad << 3) ^ swz;
    const int c1   = (32 + (quad << 3)) ^ swz;
    const int arow = ml << 6;

    bf16x8_t aA[4][2], bF[2][2];

    for (int t = 0; t < NT; ++t) {
        const int ab = (t & 1) << 13;
        const int bb = 16384 + ((t & 1) << 14);

        // ---- phase 0 ----
#pragma unroll
        for (int m = 0; m < 4; ++m) {
            const int r = ab + ((2 * m + wm) << 10) + arow;
            aA[m][0] = *(const bf16x8_t*)&lds[r + c0];
            aA[m][1] = *(const bf16x8_t*)&lds[r + c1];
        }
#pragma unroll
        for (int n = 0; n < 2; ++n) {
            const int r = bb + ((4 * n + wn) << 10) + arow;
            bF[n][0] = *(const bf16x8_t*)&lds[r + c0];
            bF[n][1] = *(const bf16x8_t*)&lds[r + c1];
        }
        if (t + 1 < NT) { stage_unit(t + 1, 1, 2); stage_unit(t + 1, 1, 3); }
        __builtin_amdgcn_s_barrier();
        asm volatile("s_waitcnt lgkmcnt(0)" ::: "memory");
        __builtin_amdgcn_sched_barrier(0);
        __builtin_amdgcn_s_setprio(1);
#pragma unroll
        for (int m = 0; m < 4; ++m)
#pragma unroll
            for (int n = 0; n < 2; ++n) {
                acc[m][n] = __builtin_amdgcn_mfma_f32_16x16x32_bf16(aA[m][0], bF[n][0], acc[m][n], 0, 0, 0);
                acc[m][n] = __builtin_amdgcn_mfma_f32_16x16x32_bf16(aA[m][1], bF[n][1], acc[m][n], 0, 0, 0);
            }
        __builtin_amdgcn_s_setprio(0);
        __builtin_amdgcn_s_barrier();

        // ---- phase 1 ----
#pragma unroll
        for (int n = 0; n < 2; ++n) {
            const int r = bb + ((4 * (n + 2) + wn) << 10) + arow;
            bF[n][0] = *(const bf16x8_t*)&lds[r + c0];
            bF[n][1] = *(const bf16x8_t*)&lds[r + c1];
        }
        if (t + 2 < NT) {
            stage_unit(t + 2, 0, 0); stage_unit(t + 2, 0, 1);
            stage_unit(t + 2, 1, 0); stage_unit(t + 2, 1, 1);
        }
        __builtin_amdgcn_s_barrier();
        asm volatile("s_waitcnt lgkmcnt(0)" ::: "memory");
        __builtin_amdgcn_sched_barrier(0);
        __builtin_amdgcn_s_setprio(1);
#pragma unroll
        for (int m = 0; m < 4; ++m)
#pragma unroll
            for (int n = 0; n < 2; ++n) {
                acc[m][2 + n] = __builtin_amdgcn_mfma_f32_16x16x32_bf16(aA[m][0], bF[n][0], acc[m][2 + n], 0, 0, 0);
                acc[m][2 + n] = __builtin_amdgcn_mfma_f32_16x16x32_bf16(aA[m][1], bF[n][1], acc[m][2 + n], 0, 0, 0);
            }
        __builtin_amdgcn_s_setprio(0);
        if (t + 2 < NT)      asm volatile("s_waitcnt vmcnt(4)" ::: "memory");
        else if (t + 1 < NT) asm volatile("s_waitcnt vmcnt(0)" ::: "memory");
        __builtin_amdgcn_s_barrier();
    }

#pragma unroll
    for (int m = 0; m < 4; ++m) {
        const int rbase = m0 + (2 * m + wm) * 16 + quad * 4;
#pragma unroll
        for (int n = 0; n < 4; ++n) {
            const int col = n0 + (4 * n + wn) * 16 + ml;
#pragma unroll
            for (int r = 0; r < 4; ++r)
                C[(size_t)(rbase + r) * ldc + col] = acc[m][n][r];
        }
    }
}

// ---------------------------------------------------------------------------
// state_kernel: per (bh,c) computes S_c = Kf^T @ V_ext (MFMA). (unchanged)
// ---------------------------------------------------------------------------
__global__ __launch_bounds__(256)
void state_kernel(const unsigned short* __restrict__ qkv, unsigned short* __restrict__ STg)
{
    __shared__ unsigned short KT[16 * LP];   // K transposed [f][j]
    __shared__ unsigned short VT[80 * LP];   // V_ext transposed [e][j]

    const int x = blockIdx.x;
    const int c = x & 15, bh = x >> 4;
    const int b = bh >> 4, h = bh & 15;
    const int tid = threadIdx.x;
    const int wave = tid >> 6, lane = tid & 63;
    const int ml = lane & 15, kg8 = (lane >> 4) * 8;
    const int quad4 = (lane >> 4) * 4;
    const size_t rowbase = (size_t)(b * LL + c * CHUNK);
    const size_t Sbase = (size_t)x * SROW;

    {
        const int rg = tid & 31, eb = tid >> 5;   // rows 4rg..4rg+3, e-block eb*8
        uint4 vv[4];
#pragma unroll
        for (int i = 0; i < 4; ++i)
            vv[i] = *(const uint4*)(qkv + (rowbase + 4 * rg + i) * QKVLD + 512 + h * 64 + eb * 8);
        const unsigned short* p0 = (const unsigned short*)&vv[0];
        const unsigned short* p1 = (const unsigned short*)&vv[1];
        const unsigned short* p2 = (const unsigned short*)&vv[2];
        const unsigned short* p3 = (const unsigned short*)&vv[3];
#pragma unroll
        for (int e = 0; e < 8; ++e) {
            ushort4 w4; w4.x = p0[e]; w4.y = p1[e]; w4.z = p2[e]; w4.w = p3[e];
            *(ushort4*)&VT[(eb * 8 + e) * LP + 4 * rg] = w4;
        }
        if (eb < 2) {   // K: 16 feature rows via tid<64
            uint4 kv4[4];
#pragma unroll
            for (int i = 0; i < 4; ++i)
                kv4[i] = *(const uint4*)(qkv + (rowbase + 4 * rg + i) * QKVLD + 256 + h * 16 + eb * 8);
            const unsigned short* k0 = (const unsigned short*)&kv4[0];
            const unsigned short* k1 = (const unsigned short*)&kv4[1];
            const unsigned short* k2 = (const unsigned short*)&kv4[2];
            const unsigned short* k3 = (const unsigned short*)&kv4[3];
#pragma unroll
            for (int e = 0; e < 8; ++e) {
                ushort4 w4; w4.x = k0[e]; w4.y = k1[e]; w4.z = k2[e]; w4.w = k3[e];
                *(ushort4*)&KT[(eb * 8 + e) * LP + 4 * rg] = w4;
            }
        }
        const int row = tid >> 1, half = tid & 1;
        if (half == 0) {
            VT[64 * LP + row] = 0x3F80;   // ones column
        } else {
#pragma unroll
            for (int e = 65; e < 80; ++e) VT[e * LP + row] = 0;
        }
    }
    __syncthreads();

    bf16x8_t bfr[5][4];
#pragma unroll
    for (int nt = 0; nt < 5; ++nt)
#pragma unroll
        for (int ks = 0; ks < 4; ++ks)
            bfr[nt][ks] = *(const bf16x8_t*)&VT[(nt * 16 + ml) * LP + ks * 32 + kg8];

    for (int mt = wave; mt < 18; mt += 4) {
        const int d = mt * 16 + ml;
        bf16x8_t af[4];
#pragma unroll
        for (int ks = 0; ks < 4; ++ks) {
            const int jb = ks * 32 + kg8;
            unsigned short o[8];
            if (d >= 24 && d < 280) {
                const int e = d - 24, a = e >> 4, bq = e & 15;
                bf16x8_t ka = *(const bf16x8_t*)&KT[a  * LP + jb];
                bf16x8_t kb = *(const bf16x8_t*)&KT[bq * LP + jb];
#pragma unroll
                for (int j = 0; j < 8; ++j)
                    o[j] = f2b(b2f((unsigned short)ka[j]) * b2f((unsigned short)kb[j]) * INV_R2RD);
            } else if (d == 0) {
#pragma unroll
                for (int j = 0; j < 8; ++j) o[j] = 0x3F80;
            } else if (d <= 16) {
                bf16x8_t kx = *(const bf16x8_t*)&KT[(d - 1) * LP + jb];
#pragma unroll
                for (int j = 0; j < 8; ++j) o[j] = f2b(b2f((unsigned short)kx[j]) * 0.5f);
            } else {
#pragma unroll
                for (int j = 0; j < 8; ++j) o[j] = 0;
            }
            af[ks] = *(const bf16x8_t*)o;
        }
        f32x4_t acc[5];
#pragma unroll
        for (int nt = 0; nt < 5; ++nt) acc[nt] = (f32x4_t){0.f, 0.f, 0.f, 0.f};
        __builtin_amdgcn_s_setprio(1);
#pragma unroll
        for (int nt = 0; nt < 5; ++nt)
#pragma unroll
            for (int ks = 0; ks < 4; ++ks)
                acc[nt] = __builtin_amdgcn_mfma_f32_16x16x32_bf16(af[ks], bfr[nt][ks], acc[nt], 0, 0, 0);
        __builtin_amdgcn_s_setprio(0);
#pragma unroll
        for (int nt = 0; nt < 5; ++nt) {
            ushort4 pk;
            pk.x = f2b(acc[nt][0]); pk.y = f2b(acc[nt][1]);
            pk.z = f2b(acc[nt][2]); pk.w = f2b(acc[nt][3]);
            if (nt < 4) {
                *(ushort4*)(STg + Sbase + (size_t)mt * 1040 + (nt * 16 + ml) * 16 + quad4) = pk;
            } else if (ml == 0) {
                *(ushort4*)(STg + Sbase + (size_t)mt * 1040 + 1024 + quad4) = pk;
            }
        }
    }
}

// ---------------------------------------------------------------------------
// scan: exclusive prefix over the 16 chunks, elementwise. (unchanged)
// ---------------------------------------------------------------------------
__global__ __launch_bounds__(256)
void scan_S(unsigned short* __restrict__ STg) {
    const int bh  = blockIdx.y;
    const int idx = blockIdx.x * 256 + threadIdx.x;   // uint4 index, 0..2339
    if (idx >= SROW / 8) return;
    const size_t base = (size_t)bh * NCHUNK * SROW + (size_t)idx * 8;
    uint4 v[NCHUNK];
#pragma unroll
    for (int c = 0; c < NCHUNK; ++c)
        v[c] = *(const uint4*)(STg + base + (size_t)c * SROW);
    float acc[8] = {};
#pragma unroll
    for (int c = 0; c < NCHUNK; ++c) {
        const unsigned short* vp = (const unsigned short*)&v[c];
        uint4 o;
        unsigned short* op = (unsigned short*)&o;
#pragma unroll
        for (int i = 0; i < 8; ++i) { op[i] = f2b(acc[i]); acc[i] += b2f(vp[i]); }
        *(uint4*)(STg + base + (size_t)c * SROW) = o;
    }
}

// ---------------------------------------------------------------------------
// out_kernel: per (bh,c), 256 threads / 4 waves.  LDS 53536 B -> 3 blocks/CU.
// Phase-2b ST ring: 3 slots / 2-deep prefetch.  NOTE (r7 post-mortem): a
// 4-slot ring needs 80 VGPRs for stf alone and SPILLS at the ~168-VGPR cap
// of 3 blocks/CU (r7: VGPR 84, WRITE_SIZE 104 MB scratch traffic, 2x time).
// 3-slot (60 VGPR) is the deepest ring that fits this occupancy point.
// ---------------------------------------------------------------------------
#define OFF_QP 0
#define OFF_KP 3088
#define OFF_VT 0
#define LPVT   144
#define OFF_A  9360
#define LPA    136

__global__ __launch_bounds__(256, 3)
void out_kernel(const unsigned short* __restrict__ qkv_ro, const unsigned short* __restrict__ STg,
                unsigned short* __restrict__ qkv_w)
{
    __shared__ unsigned short smem[26768];   // 53536 B -> 3 blocks/CU

    const int x = blockIdx.x;
    const int c = x & 15, bh = x >> 4;
    const int b = bh >> 4, h = bh & 15;
    const int tid = threadIdx.x;
    const int w = tid >> 6, lane = tid & 63;
    const int ml = lane & 15, quad = lane >> 4, kg8 = quad * 8;
    const size_t rowbase = (size_t)(b * LL + c * CHUNK);
    const size_t Sbase = (size_t)x * SROW;

    // ---- ST slice loader: tiled slab, per-mt stride 1040, per-kq 2080 ----
    const unsigned short* stp = STg + Sbase + (size_t)(quad >> 1) * 1040 + (quad & 1) * 8;
    bf16x8_t stf[3][5];
    auto ldst = [&](int kq, int slot) {
#pragma unroll
        for (int nt = 0; nt < 5; ++nt)
            stf[slot][nt] = *(const bf16x8_t*)(stp + (size_t)kq * 2080 + (nt * 16 + ml) * 16);
    };

    // ---- issue ALL long-latency loads up front (T14), coalesced ----
    const int row = tid >> 1, half = tid & 1;
    uint4 qv = *(const uint4*)(qkv_ro + (rowbase + row) * QKVLD + h * 16 + half * 8);
    uint4 kv = *(const uint4*)(qkv_ro + (rowbase + row) * QKVLD + 256 + h * 16 + half * 8);
    uint4 vreg[4];
#pragma unroll
    for (int cc = 0; cc < 4; ++cc)
        vreg[cc] = *(const uint4*)(qkv_ro + (rowbase + row) * QKVLD + 512 + h * 64 + half * 32 + cc * 8);
    ldst(0, 0);
    ldst(1, 1);

    // ---- stage Q (packed, stride 24) and K (padded, stride 40) ----
    *(uint4*)&smem[OFF_QP + row * 24 + half * 8] = qv;                       // cols 0..15
    if (half == 0) *(uint4*)&smem[OFF_QP + row * 24 + 16] = (uint4){0,0,0,0}; // cols 16..23
    if (tid < 16) smem[OFF_QP + 3072 + tid] = 0;                              // tail pad
    *(uint4*)&smem[OFF_KP + row * 40 + half * 8] = kv;
    *(uint4*)&smem[OFF_KP + row * 40 + 16 + half * 8] = (uint4){0, 0, 0, 0};  // K zero cols
    __syncthreads();

    // ---- phase 1: scores ----
    {
        bf16x8_t q0 = *(const bf16x8_t*)&smem[OFF_QP + (w * 32 + ml) * 24 + kg8];
        bf16x8_t q1 = *(const bf16x8_t*)&smem[OFF_QP + (w * 32 + 16 + ml) * 24 + kg8];
#pragma unroll
        for (int nt = 0; nt < 8; ++nt) {
            bf16x8_t kf = *(const bf16x8_t*)&smem[OFF_KP + (nt * 16 + ml) * 40 + kg8];
            f32x4_t a0 = __builtin_amdgcn_mfma_f32_16x16x32_bf16(q0, kf, (f32x4_t){0,0,0,0}, 0, 0, 0);
            f32x4_t a1 = __builtin_amdgcn_mfma_f32_16x16x32_bf16(q1, kf, (f32x4_t){0,0,0,0}, 0, 0, 0);
            const int j = nt * 16 + ml;
#pragma unroll
            for (int r = 0; r < 4; ++r) {
                int i0 = w * 32 + quad * 4 + r;
                float s0 = a0[r] * 0.25f;
                float v0 = (j <= i0) ? (1.f + s0 + 0.5f * s0 * s0) : 0.f;
                smem[OFF_A + i0 * LPA + j] = f2b(v0);
                int i1 = i0 + 16;
                float s1 = a1[r] * 0.25f;
                float v1 = (j <= i1) ? (1.f + s1 + 0.5f * s1 * s1) : 0.f;
                smem[OFF_A + i1 * LPA + j] = f2b(v1);
            }
        }
    }
    // q f32 registers for Qf build (from QP, still alive before VT overlay)
    const int r0 = w * 32 + ml, r1 = r0 + 16;
    float qA[16], qB[16];
    {
#pragma unroll
        for (int i = 0; i < 4; ++i) {
            bf16x4_t u = *(const bf16x4_t*)&smem[OFF_QP + r0 * 24 + 4 * i];
            bf16x4_t v = *(const bf16x4_t*)&smem[OFF_QP + r1 * 24 + 4 * i];
#pragma unroll
            for (int j = 0; j < 4; ++j) {
                qA[4 * i + j] = b2f((unsigned short)u[j]);
                qB[4 * i + j] = b2f((unsigned short)v[j]);
            }
        }
    }
    // quad-parity q-half select, loop-invariant over kq (hoisted)
    float qselA[8], qselB[8];
#pragma unroll
    for (int j = 0; j < 8; ++j) {
        qselA[j] = (quad & 1) ? qA[j] : qA[8 + j];
        qselB[j] = (quad & 1) ? qB[j] : qB[8 + j];
    }
    __syncthreads();   // A-writes + QP/KP reads done before VT overlay

    // ---- write VT rows 0..64 (overlays QP/KP) from registers ----
    {
#pragma unroll
        for (int cc = 0; cc < 4; ++cc) {
            const unsigned short* vp = (const unsigned short*)&vreg[cc];
#pragma unroll
            for (int i = 0; i < 8; ++i) smem[OFF_VT + (half * 32 + cc * 8 + i) * LPVT + row] = vp[i];
        }
        if (half == 0) smem[OFF_VT + 64 * LPVT + row] = 0x3F80;   // ones row
    }
    __syncthreads();

    f32x4_t acc[2][5];
#pragma unroll
    for (int mt = 0; mt < 2; ++mt)
#pragma unroll
        for (int nt = 0; nt < 5; ++nt) acc[mt][nt] = (f32x4_t){0.f, 0.f, 0.f, 0.f};

    // prefetch ST slice kq=2 (slot 2) before phase 2a
    ldst(2, 2);

    const bf16x8_t vzero = (bf16x8_t){0, 0, 0, 0, 0, 0, 0, 0};

    // ---- phase 2a: A @ V_ext ----
#pragma unroll
    for (int ks = 0; ks < 4; ++ks) {
        bf16x8_t af0 = *(const bf16x8_t*)&smem[OFF_A + (w * 32 + ml) * LPA + ks * 32 + kg8];
        bf16x8_t af1 = *(const bf16x8_t*)&smem[OFF_A + (w * 32 + 16 + ml) * LPA + ks * 32 + kg8];
        __builtin_amdgcn_s_setprio(1);
#pragma unroll
        for (int nt = 0; nt < 4; ++nt) {
            bf16x8_t bv = *(const bf16x8_t*)&smem[OFF_VT + (nt * 16 + ml) * LPVT + ks * 32 + kg8];
            acc[0][nt] = __builtin_amdgcn_mfma_f32_16x16x32_bf16(af0, bv, acc[0][nt], 0, 0, 0);
            acc[1][nt] = __builtin_amdgcn_mfma_f32_16x16x32_bf16(af1, bv, acc[1][nt], 0, 0, 0);
        }
        bf16x8_t bv4 = vzero;   // rows 65..79 are structural zeros; only ml==0 has data
        if (ml == 0) bv4 = *(const bf16x8_t*)&smem[OFF_VT + 64 * LPVT + ks * 32 + kg8];
        acc[0][4] = __builtin_amdgcn_mfma_f32_16x16x32_bf16(af0, bv4, acc[0][4], 0, 0, 0);
        acc[1][4] = __builtin_amdgcn_mfma_f32_16x16x32_bf16(af1, bv4, acc[1][4], 0, 0, 0);
        __builtin_amdgcn_s_setprio(0);
    }

    // ---- phase 2b: Qf @ S_ext, 3-slot ring, 2-deep prefetch ----
#pragma unroll
    for (int kq = 0; kq < 9; ++kq) {
        bf16x8_t qf[2];
#pragma unroll
        for (int mt = 0; mt < 2; ++mt) {
            const float* q    = (mt == 0) ? qA : qB;
            const float* qsel = (mt == 0) ? qselA : qselB;
            const int d0 = kq * 32 + kg8;
            unsigned short o[8];
            if (d0 >= 24 && d0 < 280) {
                const int i2 = 2 * kq;
                const float base = (quad == 3) ? q[i2 > 15 ? 15 : i2]
                                 : (quad == 0) ? q[i2 < 2 ? 0 : i2 - 2]
                                               : q[i2 < 1 ? 0 : i2 - 1];
                const float qa = base * INV_R2RD;
#pragma unroll
                for (int j = 0; j < 8; ++j) o[j] = f2b(qa * qsel[j]);
            } else if (d0 == 0) {
                o[0] = 0x3F80;
#pragma unroll
                for (int j = 1; j < 8; ++j) o[j] = f2b(q[j - 1] * 0.5f);
            } else if (d0 == 8) {
#pragma unroll
                for (int j = 0; j < 8; ++j) o[j] = f2b(q[7 + j] * 0.5f);
            } else if (d0 == 16) {
                o[0] = f2b(q[15] * 0.5f);
#pragma unroll
                for (int j = 1; j < 8; ++j) o[j] = 0;
            } else {
#pragma unroll
                for (int j = 0; j < 8; ++j) o[j] = 0;
            }
            qf[mt] = *(const bf16x8_t*)o;
        }
        __builtin_amdgcn_s_setprio(1);
#pragma unroll
        for (int nt = 0; nt < 5; ++nt) {
            acc[0][nt] = __builtin_amdgcn_mfma_f32_16x16x32_bf16(qf[0], stf[kq % 3][nt], acc[0][nt], 0, 0, 0);
            acc[1][nt] = __builtin_amdgcn_mfma_f32_16x16x32_bf16(qf[1], stf[kq % 3][nt], acc[1][nt], 0, 0, 0);
        }
        __builtin_amdgcn_s_setprio(0);
        if (kq + 3 < 9) ldst(kq + 3, kq % 3);
    }

    // ---- epilogue: y = num / (den + eps), den = col 64 (nt=4, ml==0 lanes) ----
#pragma unroll
    for (int mt = 0; mt < 2; ++mt) {
        float den[4];
#pragma unroll
        for (int r = 0; r < 4; ++r) den[r] = __shfl(acc[mt][4][r], lane & 48);
#pragma unroll
        for (int r = 0; r < 4; ++r) {
            const size_t grow = rowbase + w * 32 + mt * 16 + quad * 4 + r;
            const float rc = 1.f / (den[r] + EPS);
#pragma unroll
            for (int nt = 0; nt < 4; ++nt)
                qkv_w[grow * QKVLD + 512 + h * 64 + nt * 16 + ml] = f2b(acc[mt][nt][r] * rc);
        }
    }
}

// ---------------------------------------------------------------------------
extern "C" void kernel_launch(void* const* d_in, const int* in_sizes, int n_in,
                              void* d_out, int out_size, void* d_ws, size_t ws_size,
                              hipStream_t stream)
{
    (void)in_sizes; (void)n_in; (void)out_size; (void)ws_size;
    const float* hs = (const float*)d_in[0];
    const float* Wq = (const float*)d_in[1];
    const float* Wk = (const float*)d_in[2];
    const float* Wv = (const float*)d_in[3];
    const float* Wo = (const float*)d_in[4];
    float* out = (float*)d_out;

    char* ws = (char*)d_ws;
    unsigned short* STg   = (unsigned short*)ws;
    unsigned short* hs_bf = (unsigned short*)ws;
    size_t off = 47185920;
    unsigned short* qkv   = (unsigned short*)(ws + off); off += 25165824;  // 8192x1536
    unsigned short* Wqkv  = (unsigned short*)(ws + off); off += 3145728;   // 1536x1024
    unsigned short* Wo_bf = (unsigned short*)(ws + off); off += 2097152;   // total 77.6 MB

    cast_all<<<10752, 256, 0, stream>>>(hs, Wq, Wk, Wv, Wo, hs_bf, Wqkv, Wo_bf);
    gemm_bf16_192<<<dim3(8, 32), 512, 0, stream>>>(hs_bf, Wqkv, qkv,
                                                   DM, DM, DM, QKVLD);
    state_kernel<<<1024, 256, 0, stream>>>(qkv, STg);
    scan_S<<<dim3(10, 64), 256, 0, stream>>>(STg);
    out_kernel<<<1024, 256, 0, stream>>>(qkv, STg, qkv);   // y in-place over v cols
    gemm_bf16_128x256<<<dim3(4, 64), 512, 0, stream>>>(qkv + 512, Wo_bf, out,
                                                       DM, QKVLD, DM, DM);
}

// Round 9
// 193.991 us; speedup vs baseline: 1.1793x; 1.0769x over previous
//
#include <hip/hip_runtime.h>
#include <hip/hip_bf16.h>

#define BB 4
#define LL 2048
#define DM 1024
#define NH 16
#define FEAT 16
#define HD 64
#define CHUNK 128
#define NCHUNK 16
#define NEXT 65               // 64 v-cols + 1 ones-col (e=65..79 zeros dropped)
#define SROW 18720            // 18 dtiles x 65 e x 16 d = per-(bh,c) slab elems
#define EPS 1e-12f
#define INV_R2RD 0.17677669529663688f   // 1/(4*sqrt(2))
#define QKVLD 1536
#define LP 152                // state_kernel LDS row pad (us)

typedef short bf16x8_t __attribute__((ext_vector_type(8)));
typedef short bf16x4_t __attribute__((ext_vector_type(4)));
typedef float f32x4_t  __attribute__((ext_vector_type(4)));

__device__ __forceinline__ float b2f(unsigned short u) {
    union { unsigned int i; float f; } x; x.i = ((unsigned int)u) << 16; return x.f;
}
__device__ __forceinline__ unsigned short f2b(float f) {
    __hip_bfloat16 h = __float2bfloat16(f);
    return *reinterpret_cast<unsigned short*>(&h);
}

// ---------------------------------------------------------------------------
// One kernel for all fp32->bf16 casts (5 segments, compile-time boundaries).
// ---------------------------------------------------------------------------
__global__ __launch_bounds__(256)
void cast_all(const float* __restrict__ hs, const float* __restrict__ wq,
              const float* __restrict__ wk, const float* __restrict__ wv,
              const float* __restrict__ wo, unsigned short* __restrict__ hs_bf,
              unsigned short* __restrict__ wqkv, unsigned short* __restrict__ wo_bf)
{
    const int i = (blockIdx.x * 256 + threadIdx.x) * 4;
    const float* s; unsigned short* d;
    if (i < 8388608)       { s = hs + i;             d = hs_bf + i; }
    else if (i < 8650752)  { s = wq + (i - 8388608); d = wqkv + (i - 8388608); }
    else if (i < 8912896)  { s = wk + (i - 8650752); d = wqkv + 262144 + (i - 8650752); }
    else if (i < 9961472)  { s = wv + (i - 8912896); d = wqkv + 524288 + (i - 8912896); }
    else if (i < 11010048) { s = wo + (i - 9961472); d = wo_bf + (i - 9961472); }
    else return;
    float4 v = *(const float4*)s;
    ushort4 o; o.x = f2b(v.x); o.y = f2b(v.y); o.z = f2b(v.z); o.w = f2b(v.w);
    *(ushort4*)d = o;
}

// ---------------------------------------------------------------------------
// QKV GEMM: 256x192 tile, BK=64, 8-phase counted-vmcnt schedule. (unchanged)
// ---------------------------------------------------------------------------
__global__ __launch_bounds__(512, 2)
void gemm_bf16_192(const unsigned short* __restrict__ A, const unsigned short* __restrict__ Bw,
                   unsigned short* __restrict__ C, int K, int lda, int ldb, int ldc)
{
    __shared__ unsigned short lds[57344];   // 112 KiB
    const int tid  = threadIdx.x;
    const int wid  = tid >> 6, lane = tid & 63;
    const int wm   = wid >> 2, wn = wid & 3;
    const int ml   = lane & 15, quad = lane >> 4;
    const int nwg = gridDim.x * gridDim.y;
    const int lin = blockIdx.y * gridDim.x + blockIdx.x;
    const int swz_id = (lin & 7) * (nwg >> 3) + (lin >> 3);
    const int m0   = (swz_id / gridDim.x) * 256, n0 = (swz_id % gridDim.x) * 192;
    const int NT   = K >> 6;

    const int srow  = tid >> 3;
    const int scol  = ((tid & 7) ^ (srow & 7)) << 3;
    const int wbase = wid << 9;

    auto stage_unit = [&](int t, int isB, int u) {
        const unsigned short* g0 = isB ? Bw : A;
        const int ld = isB ? ldb : lda;
        const int rb = (isB ? n0 : m0) + u * 64 + srow;
        unsigned short* lb = lds + (isB ? 32768 + (t & 1) * 12288 : ((t & 1) << 14))
                             + (u << 12) + wbase;
        const unsigned short* g = g0 + (size_t)rb * ld + (t << 6) + scol;
        __builtin_amdgcn_global_load_lds((const __attribute__((address_space(1))) void*)g,
                                         (__attribute__((address_space(3))) void*)lb, 16, 0, 0);
    };

    f32x4_t acc[8][3];
#pragma unroll
    for (int i = 0; i < 8; ++i)
#pragma unroll
        for (int j = 0; j < 3; ++j) acc[i][j] = (f32x4_t){0.f, 0.f, 0.f, 0.f};

    stage_unit(0, 0, 0); stage_unit(0, 0, 1); stage_unit(0, 0, 2); stage_unit(0, 0, 3);
    stage_unit(0, 1, 0); stage_unit(0, 1, 1); stage_unit(0, 1, 2);
    stage_unit(1, 0, 0); stage_unit(1, 0, 1);
    stage_unit(1, 1, 0); stage_unit(1, 1, 1);
    stage_unit(1, 0, 2); stage_unit(1, 0, 3);
    asm volatile("s_waitcnt vmcnt(6)" ::: "memory");
    __builtin_amdgcn_s_barrier();

    const int swz  = (ml & 7) << 3;
    const int c0   = (quad << 3) ^ swz;
    const int c1   = (32 + (quad << 3)) ^ swz;
    const int arow = ml << 6;

    bf16x8_t aA[4][2], bLo[2][2], bN2[2];

    for (int t = 0; t < NT; ++t) {
        const int ab = (t & 1) << 14;
        const int bb = 32768 + (t & 1) * 12288;

        // ---- phase 0 ----
#pragma unroll
        for (int m = 0; m < 4; ++m) {
            const int r = ab + ((2 * m + wm) << 10) + arow;
            aA[m][0] = *(const bf16x8_t*)&lds[r + c0];
            aA[m][1] = *(const bf16x8_t*)&lds[r + c1];
        }
#pragma unroll
        for (int n = 0; n < 2; ++n) {
            const int r = bb + (wn * 48 + n * 16 + ml) * 64;
            bLo[n][0] = *(const bf16x8_t*)&lds[r + c0];
            bLo[n][1] = *(const bf16x8_t*)&lds[r + c1];
        }
        if (t + 1 < NT) stage_unit(t + 1, 1, 2);
        __builtin_amdgcn_s_barrier();
        asm volatile("s_waitcnt lgkmcnt(0)" ::: "memory");
        __builtin_amdgcn_sched_barrier(0);
        __builtin_amdgcn_s_setprio(1);
#pragma unroll
        for (int m = 0; m < 4; ++m)
#pragma unroll
            for (int n = 0; n < 2; ++n) {
                acc[m][n] = __builtin_amdgcn_mfma_f32_16x16x32_bf16(aA[m][0], bLo[n][0], acc[m][n], 0, 0, 0);
                acc[m][n] = __builtin_amdgcn_mfma_f32_16x16x32_bf16(aA[m][1], bLo[n][1], acc[m][n], 0, 0, 0);
            }
        __builtin_amdgcn_s_setprio(0);
        __builtin_amdgcn_s_barrier();

        // ---- phase 1 ----
        {
            const int r = bb + (wn * 48 + 32 + ml) * 64;
            bN2[0] = *(const bf16x8_t*)&lds[r + c0];
            bN2[1] = *(const bf16x8_t*)&lds[r + c1];
        }
        if (t + 2 < NT) { stage_unit(t + 2, 0, 0); stage_unit(t + 2, 0, 1); }
        __builtin_amdgcn_s_barrier();
        asm volatile("s_waitcnt lgkmcnt(0)" ::: "memory");
        __builtin_amdgcn_sched_barrier(0);
        __builtin_amdgcn_s_setprio(1);
#pragma unroll
        for (int m = 0; m < 4; ++m) {
            acc[m][2] = __builtin_amdgcn_mfma_f32_16x16x32_bf16(aA[m][0], bN2[0], acc[m][2], 0, 0, 0);
            acc[m][2] = __builtin_amdgcn_mfma_f32_16x16x32_bf16(aA[m][1], bN2[1], acc[m][2], 0, 0, 0);
        }
        __builtin_amdgcn_s_setprio(0);
        __builtin_amdgcn_s_barrier();

        // ---- phase 2 ----
#pragma unroll
        for (int m = 0; m < 4; ++m) {
            const int r = ab + ((2 * (m + 4) + wm) << 10) + arow;
            aA[m][0] = *(const bf16x8_t*)&lds[r + c0];
            aA[m][1] = *(const bf16x8_t*)&lds[r + c1];
        }
        if (t + 2 < NT) { stage_unit(t + 2, 1, 0); stage_unit(t + 2, 1, 1); }
        __builtin_amdgcn_s_barrier();
        asm volatile("s_waitcnt lgkmcnt(0)" ::: "memory");
        __builtin_amdgcn_sched_barrier(0);
        __builtin_amdgcn_s_setprio(1);
#pragma unroll
        for (int m = 0; m < 4; ++m)
#pragma unroll
            for (int n = 0; n < 2; ++n) {
                acc[4 + m][n] = __builtin_amdgcn_mfma_f32_16x16x32_bf16(aA[m][0], bLo[n][0], acc[4 + m][n], 0, 0, 0);
                acc[4 + m][n] = __builtin_amdgcn_mfma_f32_16x16x32_bf16(aA[m][1], bLo[n][1], acc[4 + m][n], 0, 0, 0);
            }
        __builtin_amdgcn_s_setprio(0);
        __builtin_amdgcn_s_barrier();

        // ---- phase 3 ----
        if (t + 2 < NT) { stage_unit(t + 2, 0, 2); stage_unit(t + 2, 0, 3); }
        __builtin_amdgcn_s_barrier();
        asm volatile("s_waitcnt lgkmcnt(0)" ::: "memory");
        __builtin_amdgcn_sched_barrier(0);
        __builtin_amdgcn_s_setprio(1);
#pragma unroll
        for (int m = 0; m < 4; ++m) {
            acc[4 + m][2] = __builtin_amdgcn_mfma_f32_16x16x32_bf16(aA[m][0], bN2[0], acc[4 + m][2], 0, 0, 0);
            acc[4 + m][2] = __builtin_amdgcn_mfma_f32_16x16x32_bf16(aA[m][1], bN2[1], acc[4 + m][2], 0, 0, 0);
        }
        __builtin_amdgcn_s_setprio(0);
        if (t + 2 < NT)      asm volatile("s_waitcnt vmcnt(6)" ::: "memory");
        else if (t + 1 < NT) asm volatile("s_waitcnt vmcnt(0)" ::: "memory");
        __builtin_amdgcn_s_barrier();
    }

#pragma unroll
    for (int m = 0; m < 8; ++m) {
        const int rbase = m0 + (2 * m + wm) * 16 + quad * 4;
#pragma unroll
        for (int n = 0; n < 3; ++n) {
            const int col = n0 + wn * 48 + n * 16 + ml;
#pragma unroll
            for (int r = 0; r < 4; ++r)
                C[(size_t)(rbase + r) * ldc + col] = f2b(acc[m][n][r]);
        }
    }
}

// ---------------------------------------------------------------------------
// 128x256-tile variant (fp32 out) for the output projection. (unchanged)
// ---------------------------------------------------------------------------
__global__ __launch_bounds__(512, 2)
void gemm_bf16_128x256(const unsigned short* __restrict__ A, const unsigned short* __restrict__ Bw,
                       float* __restrict__ C, int K, int lda, int ldb, int ldc)
{
    __shared__ unsigned short lds[49152];   // 96 KiB
    const int tid  = threadIdx.x;
    const int wid  = tid >> 6, lane = tid & 63;
    const int wm   = wid >> 2, wn = wid & 3;
    const int ml   = lane & 15, quad = lane >> 4;
    const int nwg = gridDim.x * gridDim.y;
    const int lin = blockIdx.y * gridDim.x + blockIdx.x;
    const int swz_id = (lin & 7) * (nwg >> 3) + (lin >> 3);
    const int m0   = (swz_id / gridDim.x) * 128, n0 = (swz_id % gridDim.x) * 256;
    const int NT   = K >> 6;

    const int srow  = tid >> 3;
    const int scol  = ((tid & 7) ^ (srow & 7)) << 3;
    const int wbase = wid << 9;

    auto stage_unit = [&](int t, int isB, int u) {
        const unsigned short* g0 = isB ? Bw : A;
        const int ld = isB ? ldb : lda;
        const int rb = (isB ? n0 : m0) + u * 64 + srow;
        const int k0 = t << 6;
        unsigned short* lb = lds + (isB ? 16384 : 0) + ((t & 1) << (isB ? 14 : 13))
                             + (u << 12) + wbase;
        const unsigned short* g = g0 + (size_t)rb * ld + k0 + scol;
        __builtin_amdgcn_global_load_lds((const __attribute__((address_space(1))) void*)g,
                                         (__attribute__((address_space(3))) void*)lb, 16, 0, 0);
    };

    f32x4_t acc[4][4];
#pragma unroll
    for (int i = 0; i < 4; ++i)
#pragma unroll
        for (int j = 0; j < 4; ++j) acc[i][j] = (f32x4_t){0.f, 0.f, 0.f, 0.f};

    stage_unit(0, 0, 0); stage_unit(0, 0, 1);
    stage_unit(0, 1, 0); stage_unit(0, 1, 1); stage_unit(0, 1, 2); stage_unit(0, 1, 3);
    stage_unit(1, 0, 0); stage_unit(1, 0, 1);
    stage_unit(1, 1, 0); stage_unit(1, 1, 1);
    asm volatile("s_waitcnt vmcnt(4)" ::: "memory");
    __builtin_amdgcn_s_barrier();

    const int swz  = (ml & 7) << 3;
    const int c0   = (quad << 3) ^ swz;
    const int c1   = (32 + (quad << 3)) ^ swz;
    const int arow = ml << 6;

    bf16x8_t aA[4][2], bF[2][2];

    for (int t = 0; t < NT; ++t) {
        const int ab = (t & 1) << 13;
        const int bb = 16384 + ((t & 1) << 14);

        // ---- phase 0 ----
#pragma unroll
        for (int m = 0; m < 4; ++m) {
            const int r = ab + ((2 * m + wm) << 10) + arow;
            aA[m][0] = *(const bf16x8_t*)&lds[r + c0];
            aA[m][1] = *(const bf16x8_t*)&lds[r + c1];
        }
#pragma unroll
        for (int n = 0; n < 2; ++n) {
            const int r = bb + ((4 * n + wn) << 10) + arow;
            bF[n][0] = *(const bf16x8_t*)&lds[r + c0];
            bF[n][1] = *(const bf16x8_t*)&lds[r + c1];
        }
        if (t + 1 < NT) { stage_unit(t + 1, 1, 2); stage_unit(t + 1, 1, 3); }
        __builtin_amdgcn_s_barrier();
        asm volatile("s_waitcnt lgkmcnt(0)" ::: "memory");
        __builtin_amdgcn_sched_barrier(0);
        __builtin_amdgcn_s_setprio(1);
#pragma unroll
        for (int m = 0; m < 4; ++m)
#pragma unroll
            for (int n = 0; n < 2; ++n) {
                acc[m][n] = __builtin_amdgcn_mfma_f32_16x16x32_bf16(aA[m][0], bF[n][0], acc[m][n], 0, 0, 0);
                acc[m][n] = __builtin_amdgcn_mfma_f32_16x16x32_bf16(aA[m][1], bF[n][1], acc[m][n], 0, 0, 0);
            }
        __builtin_amdgcn_s_setprio(0);
        __builtin_amdgcn_s_barrier();

        // ---- phase 1 ----
#pragma unroll
        for (int n = 0; n < 2; ++n) {
            const int r = bb + ((4 * (n + 2) + wn) << 10) + arow;
            bF[n][0] = *(const bf16x8_t*)&lds[r + c0];
            bF[n][1] = *(const bf16x8_t*)&lds[r + c1];
        }
        if (t + 2 < NT) {
            stage_unit(t + 2, 0, 0); stage_unit(t + 2, 0, 1);
            stage_unit(t + 2, 1, 0); stage_unit(t + 2, 1, 1);
        }
        __builtin_amdgcn_s_barrier();
        asm volatile("s_waitcnt lgkmcnt(0)" ::: "memory");
        __builtin_amdgcn_sched_barrier(0);
        __builtin_amdgcn_s_setprio(1);
#pragma unroll
        for (int m = 0; m < 4; ++m)
#pragma unroll
            for (int n = 0; n < 2; ++n) {
                acc[m][2 + n] = __builtin_amdgcn_mfma_f32_16x16x32_bf16(aA[m][0], bF[n][0], acc[m][2 + n], 0, 0, 0);
                acc[m][2 + n] = __builtin_amdgcn_mfma_f32_16x16x32_bf16(aA[m][1], bF[n][1], acc[m][2 + n], 0, 0, 0);
            }
        __builtin_amdgcn_s_setprio(0);
        if (t + 2 < NT)      asm volatile("s_waitcnt vmcnt(4)" ::: "memory");
        else if (t + 1 < NT) asm volatile("s_waitcnt vmcnt(0)" ::: "memory");
        __builtin_amdgcn_s_barrier();
    }

#pragma unroll
    for (int m = 0; m < 4; ++m) {
        const int rbase = m0 + (2 * m + wm) * 16 + quad * 4;
#pragma unroll
        for (int n = 0; n < 4; ++n) {
            const int col = n0 + (4 * n + wn) * 16 + ml;
#pragma unroll
            for (int r = 0; r < 4; ++r)
                C[(size_t)(rbase + r) * ldc + col] = acc[m][n][r];
        }
    }
}

// ---------------------------------------------------------------------------
// state_kernel: per (bh,c) computes S_c = Kf^T @ V_ext (MFMA). (unchanged)
// ---------------------------------------------------------------------------
__global__ __launch_bounds__(256)
void state_kernel(const unsigned short* __restrict__ qkv, unsigned short* __restrict__ STg)
{
    __shared__ unsigned short KT[16 * LP];   // K transposed [f][j]
    __shared__ unsigned short VT[80 * LP];   // V_ext transposed [e][j]

    const int x = blockIdx.x;
    const int c = x & 15, bh = x >> 4;
    const int b = bh >> 4, h = bh & 15;
    const int tid = threadIdx.x;
    const int wave = tid >> 6, lane = tid & 63;
    const int ml = lane & 15, kg8 = (lane >> 4) * 8;
    const int quad4 = (lane >> 4) * 4;
    const size_t rowbase = (size_t)(b * LL + c * CHUNK);
    const size_t Sbase = (size_t)x * SROW;

    {
        const int rg = tid & 31, eb = tid >> 5;   // rows 4rg..4rg+3, e-block eb*8
        uint4 vv[4];
#pragma unroll
        for (int i = 0; i < 4; ++i)
            vv[i] = *(const uint4*)(qkv + (rowbase + 4 * rg + i) * QKVLD + 512 + h * 64 + eb * 8);
        const unsigned short* p0 = (const unsigned short*)&vv[0];
        const unsigned short* p1 = (const unsigned short*)&vv[1];
        const unsigned short* p2 = (const unsigned short*)&vv[2];
        const unsigned short* p3 = (const unsigned short*)&vv[3];
#pragma unroll
        for (int e = 0; e < 8; ++e) {
            ushort4 w4; w4.x = p0[e]; w4.y = p1[e]; w4.z = p2[e]; w4.w = p3[e];
            *(ushort4*)&VT[(eb * 8 + e) * LP + 4 * rg] = w4;
        }
        if (eb < 2) {   // K: 16 feature rows via tid<64
            uint4 kv4[4];
#pragma unroll
            for (int i = 0; i < 4; ++i)
                kv4[i] = *(const uint4*)(qkv + (rowbase + 4 * rg + i) * QKVLD + 256 + h * 16 + eb * 8);
            const unsigned short* k0 = (const unsigned short*)&kv4[0];
            const unsigned short* k1 = (const unsigned short*)&kv4[1];
            const unsigned short* k2 = (const unsigned short*)&kv4[2];
            const unsigned short* k3 = (const unsigned short*)&kv4[3];
#pragma unroll
            for (int e = 0; e < 8; ++e) {
                ushort4 w4; w4.x = k0[e]; w4.y = k1[e]; w4.z = k2[e]; w4.w = k3[e];
                *(ushort4*)&KT[(eb * 8 + e) * LP + 4 * rg] = w4;
            }
        }
        const int row = tid >> 1, half = tid & 1;
        if (half == 0) {
            VT[64 * LP + row] = 0x3F80;   // ones column
        } else {
#pragma unroll
            for (int e = 65; e < 80; ++e) VT[e * LP + row] = 0;
        }
    }
    __syncthreads();

    bf16x8_t bfr[5][4];
#pragma unroll
    for (int nt = 0; nt < 5; ++nt)
#pragma unroll
        for (int ks = 0; ks < 4; ++ks)
            bfr[nt][ks] = *(const bf16x8_t*)&VT[(nt * 16 + ml) * LP + ks * 32 + kg8];

    for (int mt = wave; mt < 18; mt += 4) {
        const int d = mt * 16 + ml;
        bf16x8_t af[4];
#pragma unroll
        for (int ks = 0; ks < 4; ++ks) {
            const int jb = ks * 32 + kg8;
            unsigned short o[8];
            if (d >= 24 && d < 280) {
                const int e = d - 24, a = e >> 4, bq = e & 15;
                bf16x8_t ka = *(const bf16x8_t*)&KT[a  * LP + jb];
                bf16x8_t kb = *(const bf16x8_t*)&KT[bq * LP + jb];
#pragma unroll
                for (int j = 0; j < 8; ++j)
                    o[j] = f2b(b2f((unsigned short)ka[j]) * b2f((unsigned short)kb[j]) * INV_R2RD);
            } else if (d == 0) {
#pragma unroll
                for (int j = 0; j < 8; ++j) o[j] = 0x3F80;
            } else if (d <= 16) {
                bf16x8_t kx = *(const bf16x8_t*)&KT[(d - 1) * LP + jb];
#pragma unroll
                for (int j = 0; j < 8; ++j) o[j] = f2b(b2f((unsigned short)kx[j]) * 0.5f);
            } else {
#pragma unroll
                for (int j = 0; j < 8; ++j) o[j] = 0;
            }
            af[ks] = *(const bf16x8_t*)o;
        }
        f32x4_t acc[5];
#pragma unroll
        for (int nt = 0; nt < 5; ++nt) acc[nt] = (f32x4_t){0.f, 0.f, 0.f, 0.f};
        __builtin_amdgcn_s_setprio(1);
#pragma unroll
        for (int nt = 0; nt < 5; ++nt)
#pragma unroll
            for (int ks = 0; ks < 4; ++ks)
                acc[nt] = __builtin_amdgcn_mfma_f32_16x16x32_bf16(af[ks], bfr[nt][ks], acc[nt], 0, 0, 0);
        __builtin_amdgcn_s_setprio(0);
#pragma unroll
        for (int nt = 0; nt < 5; ++nt) {
            ushort4 pk;
            pk.x = f2b(acc[nt][0]); pk.y = f2b(acc[nt][1]);
            pk.z = f2b(acc[nt][2]); pk.w = f2b(acc[nt][3]);
            if (nt < 4) {
                *(ushort4*)(STg + Sbase + (size_t)mt * 1040 + (nt * 16 + ml) * 16 + quad4) = pk;
            } else if (ml == 0) {
                *(ushort4*)(STg + Sbase + (size_t)mt * 1040 + 1024 + quad4) = pk;
            }
        }
    }
}

// ---------------------------------------------------------------------------
// scan: exclusive prefix over the 16 chunks, elementwise. (unchanged)
// ---------------------------------------------------------------------------
__global__ __launch_bounds__(256)
void scan_S(unsigned short* __restrict__ STg) {
    const int bh  = blockIdx.y;
    const int idx = blockIdx.x * 256 + threadIdx.x;   // uint4 index, 0..2339
    if (idx >= SROW / 8) return;
    const size_t base = (size_t)bh * NCHUNK * SROW + (size_t)idx * 8;
    uint4 v[NCHUNK];
#pragma unroll
    for (int c = 0; c < NCHUNK; ++c)
        v[c] = *(const uint4*)(STg + base + (size_t)c * SROW);
    float acc[8] = {};
#pragma unroll
    for (int c = 0; c < NCHUNK; ++c) {
        const unsigned short* vp = (const unsigned short*)&v[c];
        uint4 o;
        unsigned short* op = (unsigned short*)&o;
#pragma unroll
        for (int i = 0; i < 8; ++i) { op[i] = f2b(acc[i]); acc[i] += b2f(vp[i]); }
        *(uint4*)(STg + base + (size_t)c * SROW) = o;
    }
}

// ---------------------------------------------------------------------------
// out_kernel: per (bh,c), 256 threads / 4 waves.  LDS 53536 B -> 3 blocks/CU.
// Phase-2b ST ring: 3 slots / 2-deep prefetch.
// r9 NOTE (spill history): __launch_bounds__(256,3) capped the allocator at
// 84 VGPR -> qA/qB/stf spilled to scratch (r7: 105 MB, r8: 50 MB of
// WRITE_SIZE vs 16 MB real stores).  Plain (256) gives the allocator the
// full budget (r5: 104 VGPR, WRITE_SIZE exactly 16 MB); LDS alone already
// caps residency at 3 blocks/CU, so the occupancy hint bought nothing.
// DO NOT re-add a second launch_bounds argument here.
// ---------------------------------------------------------------------------
#define OFF_QP 0
#define OFF_KP 3088
#define OFF_VT 0
#define LPVT   144
#define OFF_A  9360
#define LPA    136

__global__ __launch_bounds__(256)
void out_kernel(const unsigned short* __restrict__ qkv_ro, const unsigned short* __restrict__ STg,
                unsigned short* __restrict__ qkv_w)
{
    __shared__ unsigned short smem[26768];   // 53536 B -> 3 blocks/CU

    const int x = blockIdx.x;
    const int c = x & 15, bh = x >> 4;
    const int b = bh >> 4, h = bh & 15;
    const int tid = threadIdx.x;
    const int w = tid >> 6, lane = tid & 63;
    const int ml = lane & 15, quad = lane >> 4, kg8 = quad * 8;
    const size_t rowbase = (size_t)(b * LL + c * CHUNK);
    const size_t Sbase = (size_t)x * SROW;

    // ---- ST slice loader: tiled slab, per-mt stride 1040, per-kq 2080 ----
    const unsigned short* stp = STg + Sbase + (size_t)(quad >> 1) * 1040 + (quad & 1) * 8;
    bf16x8_t stf[3][5];
    auto ldst = [&](int kq, int slot) {
#pragma unroll
        for (int nt = 0; nt < 5; ++nt)
            stf[slot][nt] = *(const bf16x8_t*)(stp + (size_t)kq * 2080 + (nt * 16 + ml) * 16);
    };

    // ---- issue ALL long-latency loads up front (T14), coalesced ----
    const int row = tid >> 1, half = tid & 1;
    uint4 qv = *(const uint4*)(qkv_ro + (rowbase + row) * QKVLD + h * 16 + half * 8);
    uint4 kv = *(const uint4*)(qkv_ro + (rowbase + row) * QKVLD + 256 + h * 16 + half * 8);
    uint4 vreg[4];
#pragma unroll
    for (int cc = 0; cc < 4; ++cc)
        vreg[cc] = *(const uint4*)(qkv_ro + (rowbase + row) * QKVLD + 512 + h * 64 + half * 32 + cc * 8);
    ldst(0, 0);
    ldst(1, 1);

    // ---- stage Q (packed, stride 24) and K (padded, stride 40) ----
    *(uint4*)&smem[OFF_QP + row * 24 + half * 8] = qv;                       // cols 0..15
    if (half == 0) *(uint4*)&smem[OFF_QP + row * 24 + 16] = (uint4){0,0,0,0}; // cols 16..23
    if (tid < 16) smem[OFF_QP + 3072 + tid] = 0;                              // tail pad
    *(uint4*)&smem[OFF_KP + row * 40 + half * 8] = kv;
    *(uint4*)&smem[OFF_KP + row * 40 + 16 + half * 8] = (uint4){0, 0, 0, 0};  // K zero cols
    __syncthreads();

    // ---- phase 1: scores ----
    {
        bf16x8_t q0 = *(const bf16x8_t*)&smem[OFF_QP + (w * 32 + ml) * 24 + kg8];
        bf16x8_t q1 = *(const bf16x8_t*)&smem[OFF_QP + (w * 32 + 16 + ml) * 24 + kg8];
#pragma unroll
        for (int nt = 0; nt < 8; ++nt) {
            bf16x8_t kf = *(const bf16x8_t*)&smem[OFF_KP + (nt * 16 + ml) * 40 + kg8];
            f32x4_t a0 = __builtin_amdgcn_mfma_f32_16x16x32_bf16(q0, kf, (f32x4_t){0,0,0,0}, 0, 0, 0);
            f32x4_t a1 = __builtin_amdgcn_mfma_f32_16x16x32_bf16(q1, kf, (f32x4_t){0,0,0,0}, 0, 0, 0);
            const int j = nt * 16 + ml;
#pragma unroll
            for (int r = 0; r < 4; ++r) {
                int i0 = w * 32 + quad * 4 + r;
                float s0 = a0[r] * 0.25f;
                float v0 = (j <= i0) ? (1.f + s0 + 0.5f * s0 * s0) : 0.f;
                smem[OFF_A + i0 * LPA + j] = f2b(v0);
                int i1 = i0 + 16;
                float s1 = a1[r] * 0.25f;
                float v1 = (j <= i1) ? (1.f + s1 + 0.5f * s1 * s1) : 0.f;
                smem[OFF_A + i1 * LPA + j] = f2b(v1);
            }
        }
    }
    // q f32 registers for Qf build (from QP, still alive before VT overlay)
    const int r0 = w * 32 + ml, r1 = r0 + 16;
    float qA[16], qB[16];
    {
#pragma unroll
        for (int i = 0; i < 4; ++i) {
            bf16x4_t u = *(const bf16x4_t*)&smem[OFF_QP + r0 * 24 + 4 * i];
            bf16x4_t v = *(const bf16x4_t*)&smem[OFF_QP + r1 * 24 + 4 * i];
#pragma unroll
            for (int j = 0; j < 4; ++j) {
                qA[4 * i + j] = b2f((unsigned short)u[j]);
                qB[4 * i + j] = b2f((unsigned short)v[j]);
            }
        }
    }
    // quad-parity q-half select, loop-invariant over kq (hoisted)
    float qselA[8], qselB[8];
#pragma unroll
    for (int j = 0; j < 8; ++j) {
        qselA[j] = (quad & 1) ? qA[j] : qA[8 + j];
        qselB[j] = (quad & 1) ? qB[j] : qB[8 + j];
    }
    __syncthreads();   // A-writes + QP/KP reads done before VT overlay

    // ---- write VT rows 0..64 (overlays QP/KP) from registers ----
    {
#pragma unroll
        for (int cc = 0; cc < 4; ++cc) {
            const unsigned short* vp = (const unsigned short*)&vreg[cc];
#pragma unroll
            for (int i = 0; i < 8; ++i) smem[OFF_VT + (half * 32 + cc * 8 + i) * LPVT + row] = vp[i];
        }
        if (half == 0) smem[OFF_VT + 64 * LPVT + row] = 0x3F80;   // ones row
    }
    __syncthreads();

    f32x4_t acc[2][5];
#pragma unroll
    for (int mt = 0; mt < 2; ++mt)
#pragma unroll
        for (int nt = 0; nt < 5; ++nt) acc[mt][nt] = (f32x4_t){0.f, 0.f, 0.f, 0.f};

    // prefetch ST slice kq=2 (slot 2) before phase 2a
    ldst(2, 2);

    const bf16x8_t vzero = (bf16x8_t){0, 0, 0, 0, 0, 0, 0, 0};

    // ---- phase 2a: A @ V_ext ----
#pragma unroll
    for (int ks = 0; ks < 4; ++ks) {
        bf16x8_t af0 = *(const bf16x8_t*)&smem[OFF_A + (w * 32 + ml) * LPA + ks * 32 + kg8];
        bf16x8_t af1 = *(const bf16x8_t*)&smem[OFF_A + (w * 32 + 16 + ml) * LPA + ks * 32 + kg8];
        __builtin_amdgcn_s_setprio(1);
#pragma unroll
        for (int nt = 0; nt < 4; ++nt) {
            bf16x8_t bv = *(const bf16x8_t*)&smem[OFF_VT + (nt * 16 + ml) * LPVT + ks * 32 + kg8];
            acc[0][nt] = __builtin_amdgcn_mfma_f32_16x16x32_bf16(af0, bv, acc[0][nt], 0, 0, 0);
            acc[1][nt] = __builtin_amdgcn_mfma_f32_16x16x32_bf16(af1, bv, acc[1][nt], 0, 0, 0);
        }
        bf16x8_t bv4 = vzero;   // rows 65..79 are structural zeros; only ml==0 has data
        if (ml == 0) bv4 = *(const bf16x8_t*)&smem[OFF_VT + 64 * LPVT + ks * 32 + kg8];
        acc[0][4] = __builtin_amdgcn_mfma_f32_16x16x32_bf16(af0, bv4, acc[0][4], 0, 0, 0);
        acc[1][4] = __builtin_amdgcn_mfma_f32_16x16x32_bf16(af1, bv4, acc[1][4], 0, 0, 0);
        __builtin_amdgcn_s_setprio(0);
    }

    // ---- phase 2b: Qf @ S_ext, 3-slot ring, 2-deep prefetch ----
#pragma unroll
    for (int kq = 0; kq < 9; ++kq) {
        bf16x8_t qf[2];
#pragma unroll
        for (int mt = 0; mt < 2; ++mt) {
            const float* q    = (mt == 0) ? qA : qB;
            const float* qsel = (mt == 0) ? qselA : qselB;
            const int d0 = kq * 32 + kg8;
            unsigned short o[8];
            if (d0 >= 24 && d0 < 280) {
                const int i2 = 2 * kq;
                const float base = (quad == 3) ? q[i2 > 15 ? 15 : i2]
                                 : (quad == 0) ? q[i2 < 2 ? 0 : i2 - 2]
                                               : q[i2 < 1 ? 0 : i2 - 1];
                const float qa = base * INV_R2RD;
#pragma unroll
                for (int j = 0; j < 8; ++j) o[j] = f2b(qa * qsel[j]);
            } else if (d0 == 0) {
                o[0] = 0x3F80;
#pragma unroll
                for (int j = 1; j < 8; ++j) o[j] = f2b(q[j - 1] * 0.5f);
            } else if (d0 == 8) {
#pragma unroll
                for (int j = 0; j < 8; ++j) o[j] = f2b(q[7 + j] * 0.5f);
            } else if (d0 == 16) {
                o[0] = f2b(q[15] * 0.5f);
#pragma unroll
                for (int j = 1; j < 8; ++j) o[j] = 0;
            } else {
#pragma unroll
                for (int j = 0; j < 8; ++j) o[j] = 0;
            }
            qf[mt] = *(const bf16x8_t*)o;
        }
        __builtin_amdgcn_s_setprio(1);
#pragma unroll
        for (int nt = 0; nt < 5; ++nt) {
            acc[0][nt] = __builtin_amdgcn_mfma_f32_16x16x32_bf16(qf[0], stf[kq % 3][nt], acc[0][nt], 0, 0, 0);
            acc[1][nt] = __builtin_amdgcn_mfma_f32_16x16x32_bf16(qf[1], stf[kq % 3][nt], acc[1][nt], 0, 0, 0);
        }
        __builtin_amdgcn_s_setprio(0);
        if (kq + 3 < 9) ldst(kq + 3, kq % 3);
    }

    // ---- epilogue: y = num / (den + eps), den = col 64 (nt=4, ml==0 lanes) ----
#pragma unroll
    for (int mt = 0; mt < 2; ++mt) {
        float den[4];
#pragma unroll
        for (int r = 0; r < 4; ++r) den[r] = __shfl(acc[mt][4][r], lane & 48);
#pragma unroll
        for (int r = 0; r < 4; ++r) {
            const size_t grow = rowbase + w * 32 + mt * 16 + quad * 4 + r;
            const float rc = 1.f / (den[r] + EPS);
#pragma unroll
            for (int nt = 0; nt < 4; ++nt)
                qkv_w[grow * QKVLD + 512 + h * 64 + nt * 16 + ml] = f2b(acc[mt][nt][r] * rc);
        }
    }
}

// ---------------------------------------------------------------------------
extern "C" void kernel_launch(void* const* d_in, const int* in_sizes, int n_in,
                              void* d_out, int out_size, void* d_ws, size_t ws_size,
                              hipStream_t stream)
{
    (void)in_sizes; (void)n_in; (void)out_size; (void)ws_size;
    const float* hs = (const float*)d_in[0];
    const float* Wq = (const float*)d_in[1];
    const float* Wk = (const float*)d_in[2];
    const float* Wv = (const float*)d_in[3];
    const float* Wo = (const float*)d_in[4];
    float* out = (float*)d_out;

    char* ws = (char*)d_ws;
    unsigned short* STg   = (unsigned short*)ws;
    unsigned short* hs_bf = (unsigned short*)ws;
    size_t off = 47185920;
    unsigned short* qkv   = (unsigned short*)(ws + off); off += 25165824;  // 8192x1536
    unsigned short* Wqkv  = (unsigned short*)(ws + off); off += 3145728;   // 1536x1024
    unsigned short* Wo_bf = (unsigned short*)(ws + off); off += 2097152;   // total 77.6 MB

    cast_all<<<10752, 256, 0, stream>>>(hs, Wq, Wk, Wv, Wo, hs_bf, Wqkv, Wo_bf);
    gemm_bf16_192<<<dim3(8, 32), 512, 0, stream>>>(hs_bf, Wqkv, qkv,
                                                   DM, DM, DM, QKVLD);
    state_kernel<<<1024, 256, 0, stream>>>(qkv, STg);
    scan_S<<<dim3(10, 64), 256, 0, stream>>>(STg);
    out_kernel<<<1024, 256, 0, stream>>>(qkv, STg, qkv);   // y in-place over v cols
    gemm_bf16_128x256<<<dim3(4, 64), 512, 0, stream>>>(qkv + 512, Wo_bf, out,
                                                       DM, QKVLD, DM, DM);
}